// Round 1
// baseline (562.448 us; speedup 1.0000x reference)
//
#include <hip/hip_runtime.h>
#include <hip/hip_bf16.h>
#include <stdint.h>

#define BB 4
#define NN 4096
#define DD 1024
#define EE 8
#define MM 512
#define BN (BB*NN)   // 16384

// ---------------- ws layout (bytes) ----------------
// gates    : 0          size BN*EE*4   = 524288
// topk_val : 524288     size 32*512*4  = 65536
// win      : 589824     size BN*4      = 65536
// counts   : 655360     size 128 (pad to 256)
// lists    : 655616     size 32*512*4  = 65536
// total ~ 721 KB

__global__ __launch_bounds__(256) void init_kernel(int* __restrict__ win, int* __restrict__ counts) {
    int i = blockIdx.x * 256 + threadIdx.x;
    if (i < BN) win[i] = -1;
    if (i < 32) counts[i] = 0;
}

// one wave per token: logits = x[tok] . gate_w[:,e], t = log(max(.,1e-6))
__global__ __launch_bounds__(256) void gate_logits_kernel(const float* __restrict__ x,
                                                          const float* __restrict__ gw,
                                                          float* __restrict__ tmat) {
    __shared__ float gwT[EE][DD];   // transposed: bank-conflict-free reads
    int tid = threadIdx.x;
    for (int i = tid; i < DD * EE; i += 256) {
        int k = i >> 3, e = i & 7;
        gwT[e][k] = gw[i];
    }
    __syncthreads();
    int wave = tid >> 6, lane = tid & 63;
    int t = blockIdx.x * 4 + wave;           // global token 0..16383
    const float* xr = x + (size_t)t * DD;
    float acc[EE];
#pragma unroll
    for (int e = 0; e < EE; e++) acc[e] = 0.f;
    for (int j = 0; j < 16; j++) {
        int k = lane + 64 * j;
        float xv = xr[k];
#pragma unroll
        for (int e = 0; e < EE; e++) acc[e] += xv * gwT[e][k];
    }
#pragma unroll
    for (int e = 0; e < EE; e++) {
        float v = acc[e];
        for (int off = 32; off > 0; off >>= 1) v += __shfl_down(v, off, 64);
        if (lane == 0) tmat[(size_t)t * EE + e] = logf(fmaxf(v, 1e-6f));
    }
}

// one block per batch: 8 sinkhorn iterations fully in registers + block reductions
__global__ __launch_bounds__(1024) void sinkhorn_kernel(float* __restrict__ tmat) {
    int b = blockIdx.x;
    int tid = threadIdx.x;
    int wave = tid >> 6, lane = tid & 63;
    float* tb = tmat + (size_t)b * NN * EE;
    float tv[4][EE];
#pragma unroll
    for (int j = 0; j < 4; j++) {
        const float* row = tb + (size_t)(tid + 1024 * j) * EE;
#pragma unroll
        for (int e = 0; e < EE; e++) tv[j][e] = row[e];
    }
    __shared__ float red[16][8];
    __shared__ float bc[8];
    for (int it = 0; it < 8; it++) {
        // ---- column logsumexp over n (axis=-2) ----
        float cm[EE];
#pragma unroll
        for (int e = 0; e < EE; e++) {
            float m = tv[0][e];
#pragma unroll
            for (int j = 1; j < 4; j++) m = fmaxf(m, tv[j][e]);
            for (int off = 32; off > 0; off >>= 1) m = fmaxf(m, __shfl_down(m, off, 64));
            cm[e] = m;
        }
        if (lane == 0) {
#pragma unroll
            for (int e = 0; e < EE; e++) red[wave][e] = cm[e];
        }
        __syncthreads();
        if (tid < 8) {
            float m = red[0][tid];
#pragma unroll
            for (int w = 1; w < 16; w++) m = fmaxf(m, red[w][tid]);
            bc[tid] = m;
        }
        __syncthreads();
#pragma unroll
        for (int e = 0; e < EE; e++) cm[e] = bc[e];
        __syncthreads();
        float cs[EE];
#pragma unroll
        for (int e = 0; e < EE; e++) {
            float s = 0.f;
#pragma unroll
            for (int j = 0; j < 4; j++) s += expf(tv[j][e] - cm[e]);
            for (int off = 32; off > 0; off >>= 1) s += __shfl_down(s, off, 64);
            cs[e] = s;
        }
        if (lane == 0) {
#pragma unroll
            for (int e = 0; e < EE; e++) red[wave][e] = cs[e];
        }
        __syncthreads();
        if (tid < 8) {
            float s = 0.f;
#pragma unroll
            for (int w = 0; w < 16; w++) s += red[w][tid];
            bc[tid] = s;
        }
        __syncthreads();
#pragma unroll
        for (int e = 0; e < EE; e++) {
            float lse = cm[e] + logf(bc[e]);
#pragma unroll
            for (int j = 0; j < 4; j++) tv[j][e] -= lse;
        }
        __syncthreads();   // protect red/bc before next iteration
        // ---- row logsumexp over e (axis=-1), per-thread ----
#pragma unroll
        for (int j = 0; j < 4; j++) {
            float m = tv[j][0];
#pragma unroll
            for (int e = 1; e < EE; e++) m = fmaxf(m, tv[j][e]);
            float s = 0.f;
#pragma unroll
            for (int e = 0; e < EE; e++) s += expf(tv[j][e] - m);
            float lse = m + logf(s);
#pragma unroll
            for (int e = 0; e < EE; e++) tv[j][e] -= lse;
        }
    }
    // gates = exp(t)
#pragma unroll
    for (int j = 0; j < 4; j++) {
        float* row = tb + (size_t)(tid + 1024 * j) * EE;
#pragma unroll
        for (int e = 0; e < EE; e++) row[e] = expf(tv[j][e]);
    }
}

// one block per (b,e): full bitonic sort (desc, stable by smaller token) of 4096 gates
__global__ __launch_bounds__(512) void topk_kernel(const float* __restrict__ gates,
                                                   float* __restrict__ topk_val,
                                                   int* __restrict__ win) {
    __shared__ unsigned long long key[NN];
    int be = blockIdx.x;
    int b = be >> 3, e = be & 7;
    int tid = threadIdx.x;
    const float* gb = gates + (size_t)b * NN * EE + e;
    for (int t = tid; t < NN; t += 512) {
        float g = gb[(size_t)t * EE];     // g in (0,1], positive: uint order == float order
        unsigned int fb = __float_as_uint(g);
        key[t] = ((unsigned long long)fb << 32) | (unsigned int)(~t);
    }
    for (unsigned k = 2; k <= (unsigned)NN; k <<= 1) {
        for (unsigned j = k >> 1; j > 0; j >>= 1) {
            __syncthreads();
            for (unsigned i = tid; i < (unsigned)NN; i += 512) {
                unsigned l = i ^ j;
                if (l > i) {
                    unsigned long long a = key[i], c = key[l];
                    bool up = ((i & k) == 0);
                    if (up ? (a < c) : (a > c)) { key[i] = c; key[l] = a; }
                }
            }
        }
    }
    __syncthreads();
    // first 512 = top-k, rank = position
    {
        unsigned long long kk = key[tid];
        float v = __uint_as_float((unsigned int)(kk >> 32));
        int tok = (int)(~(unsigned int)kk);
        topk_val[be * MM + tid] = v;
        // numpy/XLA-CPU scatter: last write in C-order over (m,e) wins -> max code
        atomicMax(&win[b * NN + tok], tid * 8 + e);
    }
}

// resolve winner -> active flag + compacted per-(b,e) token lists
__global__ __launch_bounds__(256) void build_lists_kernel(const float* __restrict__ topk_val,
                                                          int* __restrict__ win,
                                                          int* __restrict__ counts,
                                                          int* __restrict__ lists) {
    int i = blockIdx.x * 256 + threadIdx.x;
    if (i >= BN) return;
    int b = i >> 12, tok = i & 4095;
    int w = win[i];
    int active = 0;
    if (w >= 0) {
        int m = w >> 3, e = w & 7;
        float gv = topk_val[(b * 8 + e) * MM + m];
        if (gv > 0.5f) {
            int p = atomicAdd(&counts[b * 8 + e], 1);
            lists[(b * 8 + e) * MM + p] = tok;
            active = 1;
        }
    }
    win[i] = active;   // reuse as per-token active flag
}

// zero rows of y for tokens that get no (hard) expert output
__global__ __launch_bounds__(256) void zero_inactive_kernel(const int* __restrict__ act,
                                                            float* __restrict__ y) {
    int t = blockIdx.x;
    if (act[t]) return;
    float4* row = (float4*)(y + (size_t)t * DD);
    row[threadIdx.x] = make_float4(0.f, 0.f, 0.f, 0.f);
}

// gathered GEMM per (b,e): y[b,tok,:] = x[b,tok,:] @ experts[e]   (64x64 tile, fp32)
__global__ __launch_bounds__(256) void expert_gemm_kernel(const float* __restrict__ x,
                                                          const float* __restrict__ experts,
                                                          const int* __restrict__ counts,
                                                          const int* __restrict__ lists,
                                                          float* __restrict__ y) {
    int be = blockIdx.z;
    int b = be >> 3, e = be & 7;
    int cnt = counts[be];
    int row0 = blockIdx.y * 64;
    if (row0 >= cnt) return;
    int col0 = blockIdx.x * 64;

    __shared__ float As[16][68];   // [k][row], padded
    __shared__ float Bs[16][68];   // [k][col], padded
    __shared__ int toks[64];

    int tid = threadIdx.x;
    if (tid < 64) {
        int r = row0 + tid;
        toks[tid] = (r < cnt) ? lists[be * MM + r] : -1;
    }
    __syncthreads();

    int tx = tid & 15, ty = tid >> 4;
    int ar = tid >> 2;            // A-load row 0..63
    int ak = (tid & 3) * 4;       // A-load k offset
    int bk = tid >> 4;            // B-load k 0..15
    int bc4 = (tid & 15) * 4;     // B-load col offset
    int atok = toks[ar];
    const float* xb = x + (size_t)b * NN * DD;
    const float* Eb = experts + (size_t)e * DD * DD + col0;

    float acc[4][4] = {};
    for (int k0 = 0; k0 < DD; k0 += 16) {
        float4 av;
        if (atok >= 0) av = *(const float4*)(xb + (size_t)atok * DD + k0 + ak);
        else av = make_float4(0.f, 0.f, 0.f, 0.f);
        float4 bv = *(const float4*)(Eb + (size_t)(k0 + bk) * DD + bc4);
        __syncthreads();
        As[ak + 0][ar] = av.x; As[ak + 1][ar] = av.y; As[ak + 2][ar] = av.z; As[ak + 3][ar] = av.w;
        *(float4*)&Bs[bk][bc4] = bv;
        __syncthreads();
#pragma unroll
        for (int kk = 0; kk < 16; kk++) {
            float4 a = *(const float4*)&As[kk][ty * 4];
            float4 bb = *(const float4*)&Bs[kk][tx * 4];
            acc[0][0] += a.x * bb.x; acc[0][1] += a.x * bb.y; acc[0][2] += a.x * bb.z; acc[0][3] += a.x * bb.w;
            acc[1][0] += a.y * bb.x; acc[1][1] += a.y * bb.y; acc[1][2] += a.y * bb.z; acc[1][3] += a.y * bb.w;
            acc[2][0] += a.z * bb.x; acc[2][1] += a.z * bb.y; acc[2][2] += a.z * bb.z; acc[2][3] += a.z * bb.w;
            acc[3][0] += a.w * bb.x; acc[3][1] += a.w * bb.y; acc[3][2] += a.w * bb.z; acc[3][3] += a.w * bb.w;
        }
    }
#pragma unroll
    for (int i = 0; i < 4; i++) {
        int rl = ty * 4 + i;
        if (row0 + rl < cnt) {
            int tok = toks[rl];
            float4 o = make_float4(acc[i][0], acc[i][1], acc[i][2], acc[i][3]);
            *(float4*)(y + ((size_t)b * NN + tok) * DD + col0 + tx * 4) = o;
        }
    }
}

extern "C" void kernel_launch(void* const* d_in, const int* in_sizes, int n_in,
                              void* d_out, int out_size, void* d_ws, size_t ws_size,
                              hipStream_t stream) {
    const float* x       = (const float*)d_in[0];
    const float* gw      = (const float*)d_in[1];
    const float* experts = (const float*)d_in[2];
    float* y = (float*)d_out;

    char* ws = (char*)d_ws;
    float* gates    = (float*)(ws);
    float* topk_val = (float*)(ws + 524288);
    int*   win      = (int*)(ws + 589824);
    int*   counts   = (int*)(ws + 655360);
    int*   lists    = (int*)(ws + 655616);

    init_kernel<<<64, 256, 0, stream>>>(win, counts);
    gate_logits_kernel<<<BN / 4, 256, 0, stream>>>(x, gw, gates);
    sinkhorn_kernel<<<BB, 1024, 0, stream>>>(gates);
    topk_kernel<<<BB * EE, 512, 0, stream>>>(gates, topk_val, win);
    build_lists_kernel<<<BN / 256, 256, 0, stream>>>(topk_val, win, counts, lists);
    zero_inactive_kernel<<<BN, 256, 0, stream>>>(win, y);
    expert_gemm_kernel<<<dim3(16, 8, BB * EE), 256, 0, stream>>>(x, experts, counts, lists, y);
}

// Round 2
// 401.646 us; speedup vs baseline: 1.4004x; 1.4004x over previous
//
#include <hip/hip_runtime.h>
#include <hip/hip_bf16.h>
#include <stdint.h>

#define BB 4
#define NN 4096
#define DD 1024
#define EE 8
#define MM 512
#define BN (BB*NN)   // 16384

typedef __bf16 bf16x8 __attribute__((ext_vector_type(8)));
typedef float  floatx4 __attribute__((ext_vector_type(4)));

typedef const __attribute__((address_space(1))) void* gptr_t;
typedef __attribute__((address_space(3))) void* lptr_t;

__device__ __forceinline__ unsigned short f2bf(float f) {
    union { float f; unsigned u; } v; v.f = f;
    unsigned r = v.u + 0x7fffu + ((v.u >> 16) & 1u);   // round-to-nearest-even
    return (unsigned short)(r >> 16);
}

// ---------------- ws layout (bytes) ----------------
#define OFF_GATES   0u
#define OFF_TOPK    524288u
#define OFF_WIN     589824u
#define OFF_COUNTS  655360u
#define OFF_LISTS   655616u
#define OFF_XBF     721152u                       // BN*DD*2 = 33554432
#define OFF_EXPT    (OFF_XBF + 33554432u)         // EE*DD*DD*2 = 16777216
#define WS_NEEDED   (OFF_EXPT + 16777216u)        // ~48.7 MB

__global__ __launch_bounds__(256) void init_kernel(int* __restrict__ win, int* __restrict__ counts) {
    int i = blockIdx.x * 256 + threadIdx.x;
    if (i < BN) win[i] = -1;
    if (i < 32) counts[i] = 0;
}

// one wave per token: logits = x[tok] . gate_w[:,e]; also emit x in bf16
__global__ __launch_bounds__(256) void gate_logits_kernel(const float* __restrict__ x,
                                                          const float* __restrict__ gw,
                                                          float* __restrict__ tmat,
                                                          unsigned short* __restrict__ xbf) {
    __shared__ float gwT[EE][DD];   // transposed
    int tid = threadIdx.x;
    for (int i = tid; i < DD * EE; i += 256) {
        int k = i >> 3, e = i & 7;
        gwT[e][k] = gw[i];
    }
    __syncthreads();
    int wave = tid >> 6, lane = tid & 63;
    int t = blockIdx.x * 4 + wave;           // global token 0..16383
    const float4* xr = (const float4*)(x + (size_t)t * DD);
    ushort4* xo = xbf ? (ushort4*)(xbf + (size_t)t * DD) : nullptr;
    float acc[EE];
#pragma unroll
    for (int e = 0; e < EE; e++) acc[e] = 0.f;
#pragma unroll
    for (int jj = 0; jj < 4; jj++) {
        int k4 = jj * 64 + lane;             // float4 chunk index 0..255
        float4 v = xr[k4];
        if (xo) {
            ushort4 o; o.x = f2bf(v.x); o.y = f2bf(v.y); o.z = f2bf(v.z); o.w = f2bf(v.w);
            xo[k4] = o;
        }
        int k = k4 * 4;
#pragma unroll
        for (int e = 0; e < EE; e++)
            acc[e] += v.x * gwT[e][k] + v.y * gwT[e][k + 1] + v.z * gwT[e][k + 2] + v.w * gwT[e][k + 3];
    }
#pragma unroll
    for (int e = 0; e < EE; e++) {
        float v = acc[e];
        for (int off = 32; off > 0; off >>= 1) v += __shfl_down(v, off, 64);
        if (lane == 0) tmat[(size_t)t * EE + e] = logf(fmaxf(v, 1e-6f));
    }
}

// experts[e][k][col] fp32 -> expt[e][col][k] bf16 (transposed, for B^T staging)
__global__ __launch_bounds__(256) void conv_experts_kernel(const float* __restrict__ E,
                                                           unsigned short* __restrict__ expt) {
    __shared__ float tile[32][33];
    int e = blockIdx.z, k0 = blockIdx.x * 32, c0 = blockIdx.y * 32;
    int tid = threadIdx.x;
    int r = tid >> 3, c4 = (tid & 7) * 4;
    float4 v = *(const float4*)(E + ((size_t)e * DD + k0 + r) * DD + c0 + c4);
    tile[r][c4 + 0] = v.x; tile[r][c4 + 1] = v.y; tile[r][c4 + 2] = v.z; tile[r][c4 + 3] = v.w;
    __syncthreads();
    int cc = tid >> 3, k4 = (tid & 7) * 4;
    ushort4 o;
    o.x = f2bf(tile[k4 + 0][cc]); o.y = f2bf(tile[k4 + 1][cc]);
    o.z = f2bf(tile[k4 + 2][cc]); o.w = f2bf(tile[k4 + 3][cc]);
    *(ushort4*)&expt[((size_t)e * DD + c0 + cc) * DD + k0 + k4] = o;
}

// one block per batch: 8 sinkhorn iterations in registers + block reductions
__global__ __launch_bounds__(1024) void sinkhorn_kernel(float* __restrict__ tmat) {
    int b = blockIdx.x;
    int tid = threadIdx.x;
    int wave = tid >> 6, lane = tid & 63;
    float* tb = tmat + (size_t)b * NN * EE;
    float tv[4][EE];
#pragma unroll
    for (int j = 0; j < 4; j++) {
        const float* row = tb + (size_t)(tid + 1024 * j) * EE;
#pragma unroll
        for (int e = 0; e < EE; e++) tv[j][e] = row[e];
    }
    __shared__ float red[16][8];
    __shared__ float bc[8];
    for (int it = 0; it < 8; it++) {
        float cm[EE];
#pragma unroll
        for (int e = 0; e < EE; e++) {
            float m = tv[0][e];
#pragma unroll
            for (int j = 1; j < 4; j++) m = fmaxf(m, tv[j][e]);
            for (int off = 32; off > 0; off >>= 1) m = fmaxf(m, __shfl_down(m, off, 64));
            cm[e] = m;
        }
        if (lane == 0) {
#pragma unroll
            for (int e = 0; e < EE; e++) red[wave][e] = cm[e];
        }
        __syncthreads();
        if (tid < 8) {
            float m = red[0][tid];
#pragma unroll
            for (int w = 1; w < 16; w++) m = fmaxf(m, red[w][tid]);
            bc[tid] = m;
        }
        __syncthreads();
#pragma unroll
        for (int e = 0; e < EE; e++) cm[e] = bc[e];
        __syncthreads();
        float cs[EE];
#pragma unroll
        for (int e = 0; e < EE; e++) {
            float s = 0.f;
#pragma unroll
            for (int j = 0; j < 4; j++) s += expf(tv[j][e] - cm[e]);
            for (int off = 32; off > 0; off >>= 1) s += __shfl_down(s, off, 64);
            cs[e] = s;
        }
        if (lane == 0) {
#pragma unroll
            for (int e = 0; e < EE; e++) red[wave][e] = cs[e];
        }
        __syncthreads();
        if (tid < 8) {
            float s = 0.f;
#pragma unroll
            for (int w = 0; w < 16; w++) s += red[w][tid];
            bc[tid] = s;
        }
        __syncthreads();
#pragma unroll
        for (int e = 0; e < EE; e++) {
            float lse = cm[e] + logf(bc[e]);
#pragma unroll
            for (int j = 0; j < 4; j++) tv[j][e] -= lse;
        }
        __syncthreads();
#pragma unroll
        for (int j = 0; j < 4; j++) {
            float m = tv[j][0];
#pragma unroll
            for (int e = 1; e < EE; e++) m = fmaxf(m, tv[j][e]);
            float s = 0.f;
#pragma unroll
            for (int e = 0; e < EE; e++) s += expf(tv[j][e] - m);
            float lse = m + logf(s);
#pragma unroll
            for (int e = 0; e < EE; e++) tv[j][e] -= lse;
        }
    }
#pragma unroll
    for (int j = 0; j < 4; j++) {
        float* row = tb + (size_t)(tid + 1024 * j) * EE;
#pragma unroll
        for (int e = 0; e < EE; e++) row[e] = expf(tv[j][e]);
    }
}

// one block per (b,e): full bitonic sort (desc, stable) of 4096 gates
__global__ __launch_bounds__(1024) void topk_kernel(const float* __restrict__ gates,
                                                    float* __restrict__ topk_val,
                                                    int* __restrict__ win) {
    __shared__ unsigned long long key[NN];
    int be = blockIdx.x;
    int b = be >> 3, e = be & 7;
    int tid = threadIdx.x;
    const float* gb = gates + (size_t)b * NN * EE + e;
    for (int t = tid; t < NN; t += 1024) {
        float g = gb[(size_t)t * EE];     // g in (0,1]: uint order == float order
        unsigned int fb = __float_as_uint(g);
        key[t] = ((unsigned long long)fb << 32) | (unsigned int)(~t);
    }
    for (unsigned k = 2; k <= (unsigned)NN; k <<= 1) {
        for (unsigned j = k >> 1; j > 0; j >>= 1) {
            __syncthreads();
            for (unsigned i = tid; i < (unsigned)NN; i += 1024) {
                unsigned l = i ^ j;
                if (l > i) {
                    unsigned long long a = key[i], c = key[l];
                    bool up = ((i & k) == 0);
                    if (up ? (a < c) : (a > c)) { key[i] = c; key[l] = a; }
                }
            }
        }
    }
    __syncthreads();
    if (tid < MM) {
        unsigned long long kk = key[tid];
        float v = __uint_as_float((unsigned int)(kk >> 32));
        int tok = (int)(~(unsigned int)kk);
        topk_val[be * MM + tid] = v;
        // numpy scatter: last write in C-order over (m,e) wins -> max code wins
        atomicMax(&win[b * NN + tok], tid * 8 + e);
    }
}

__global__ __launch_bounds__(256) void build_lists_kernel(const float* __restrict__ topk_val,
                                                          int* __restrict__ win,
                                                          int* __restrict__ counts,
                                                          int* __restrict__ lists) {
    int i = blockIdx.x * 256 + threadIdx.x;
    if (i >= BN) return;
    int b = i >> 12, tok = i & 4095;
    int w = win[i];
    int active = 0;
    if (w >= 0) {
        int m = w >> 3, e = w & 7;
        float gv = topk_val[(b * 8 + e) * MM + m];
        if (gv > 0.5f) {
            int p = atomicAdd(&counts[b * 8 + e], 1);
            lists[(b * 8 + e) * MM + p] = tok;
            active = 1;
        }
    }
    win[i] = active;
}

__global__ __launch_bounds__(256) void zero_inactive_kernel(const int* __restrict__ act,
                                                            float* __restrict__ y) {
    int t = blockIdx.x;
    if (act[t]) return;
    float4* row = (float4*)(y + (size_t)t * DD);
    row[threadIdx.x] = make_float4(0.f, 0.f, 0.f, 0.f);
}

// ---------- bf16 MFMA gathered GEMM: y[b,tok,:] = xbf[b,tok,:] @ expt[e]^T ----------
// 128x128 tile, BK=32, 4 waves in 2x2, each wave 4x4 of 16x16x32 MFMA
__global__ __launch_bounds__(256) void expert_gemm_mfma(const unsigned short* __restrict__ xbf,
                                                        const unsigned short* __restrict__ expt,
                                                        const int* __restrict__ counts,
                                                        const int* __restrict__ lists,
                                                        float* __restrict__ y) {
    int be = blockIdx.z;
    int b = be >> 3, e = be & 7;
    int cnt = counts[be];
    int row0 = blockIdx.y * 128;
    if (row0 >= cnt) return;
    int col0 = blockIdx.x * 128;

    __shared__ unsigned short As[128 * 32];   // [row][k]  8 KB
    __shared__ unsigned short Bs[128 * 32];   // [col][k]  8 KB
    __shared__ int toks[128];

    int tid = threadIdx.x;
    int wave = tid >> 6, lane = tid & 63;
    int m16 = lane & 15, quad = lane >> 4;
    int wave_m = wave >> 1, wave_n = wave & 1;

    if (tid < 128) {
        int r = row0 + tid;
        toks[tid] = lists[be * MM + (r < cnt ? r : cnt - 1)];
    }

    int r0 = tid >> 2;          // 0..63 (staging row/col)
    int ch = tid & 3;           // 16B chunk (8 bf16)

    const unsigned short* xb = xbf + (size_t)b * NN * DD;
    const unsigned short* Eb = expt + (size_t)e * DD * DD;

    floatx4 acc[4][4];
#pragma unroll
    for (int i = 0; i < 4; i++)
#pragma unroll
        for (int j = 0; j < 4; j++) acc[i][j] = (floatx4)0.f;

    for (int k0 = 0; k0 < DD; k0 += 32) {
        __syncthreads();   // previous compute done (and toks visible on iter 0)
        {
            const unsigned short* gA0 = xb + (size_t)toks[r0] * DD + k0 + ch * 8;
            const unsigned short* gA1 = xb + (size_t)toks[64 + r0] * DD + k0 + ch * 8;
            const unsigned short* gB0 = Eb + (size_t)(col0 + r0) * DD + k0 + ch * 8;
            const unsigned short* gB1 = Eb + (size_t)(col0 + 64 + r0) * DD + k0 + ch * 8;
            __builtin_amdgcn_global_load_lds((gptr_t)gA0, (lptr_t)(As + (size_t)tid * 8), 16, 0, 0);
            __builtin_amdgcn_global_load_lds((gptr_t)gA1, (lptr_t)(As + 64 * 32 + (size_t)tid * 8), 16, 0, 0);
            __builtin_amdgcn_global_load_lds((gptr_t)gB0, (lptr_t)(Bs + (size_t)tid * 8), 16, 0, 0);
            __builtin_amdgcn_global_load_lds((gptr_t)gB1, (lptr_t)(Bs + 64 * 32 + (size_t)tid * 8), 16, 0, 0);
        }
        __syncthreads();   // drains vmcnt before any LDS read
        bf16x8 af[4], bfr[4];
#pragma unroll
        for (int i = 0; i < 4; i++)
            af[i] = *(const bf16x8*)&As[(wave_m * 64 + i * 16 + m16) * 32 + quad * 8];
#pragma unroll
        for (int j = 0; j < 4; j++)
            bfr[j] = *(const bf16x8*)&Bs[(wave_n * 64 + j * 16 + m16) * 32 + quad * 8];
#pragma unroll
        for (int i = 0; i < 4; i++)
#pragma unroll
            for (int j = 0; j < 4; j++)
                acc[i][j] = __builtin_amdgcn_mfma_f32_16x16x32_bf16(af[i], bfr[j], acc[i][j], 0, 0, 0);
    }

    // epilogue: C/D layout col=lane&15, row=quad*4+reg
#pragma unroll
    for (int i = 0; i < 4; i++) {
#pragma unroll
        for (int r = 0; r < 4; r++) {
            int lr = wave_m * 64 + i * 16 + quad * 4 + r;
            if (row0 + lr < cnt) {
                int tok = toks[lr];
                float* yr = y + ((size_t)b * NN + tok) * DD + col0 + wave_n * 64 + m16;
#pragma unroll
                for (int j = 0; j < 4; j++) yr[j * 16] = acc[i][j][r];
            }
        }
    }
}

// fallback fp32 GEMM (used only if ws too small for bf16 buffers)
__global__ __launch_bounds__(256) void expert_gemm_kernel(const float* __restrict__ x,
                                                          const float* __restrict__ experts,
                                                          const int* __restrict__ counts,
                                                          const int* __restrict__ lists,
                                                          float* __restrict__ y) {
    int be = blockIdx.z;
    int b = be >> 3, e = be & 7;
    int cnt = counts[be];
    int row0 = blockIdx.y * 64;
    if (row0 >= cnt) return;
    int col0 = blockIdx.x * 64;
    __shared__ float As[16][68];
    __shared__ float Bs[16][68];
    __shared__ int toks[64];
    int tid = threadIdx.x;
    if (tid < 64) {
        int r = row0 + tid;
        toks[tid] = (r < cnt) ? lists[be * MM + r] : -1;
    }
    __syncthreads();
    int tx = tid & 15, ty = tid >> 4;
    int ar = tid >> 2;
    int ak = (tid & 3) * 4;
    int bk = tid >> 4;
    int bc4 = (tid & 15) * 4;
    int atok = toks[ar];
    const float* xb = x + (size_t)b * NN * DD;
    const float* Eb = experts + (size_t)e * DD * DD + col0;
    float acc[4][4] = {};
    for (int k0 = 0; k0 < DD; k0 += 16) {
        float4 av;
        if (atok >= 0) av = *(const float4*)(xb + (size_t)atok * DD + k0 + ak);
        else av = make_float4(0.f, 0.f, 0.f, 0.f);
        float4 bv = *(const float4*)(Eb + (size_t)(k0 + bk) * DD + bc4);
        __syncthreads();
        As[ak + 0][ar] = av.x; As[ak + 1][ar] = av.y; As[ak + 2][ar] = av.z; As[ak + 3][ar] = av.w;
        *(float4*)&Bs[bk][bc4] = bv;
        __syncthreads();
#pragma unroll
        for (int kk = 0; kk < 16; kk++) {
            float4 a = *(const float4*)&As[kk][ty * 4];
            float4 bb = *(const float4*)&Bs[kk][tx * 4];
            acc[0][0] += a.x * bb.x; acc[0][1] += a.x * bb.y; acc[0][2] += a.x * bb.z; acc[0][3] += a.x * bb.w;
            acc[1][0] += a.y * bb.x; acc[1][1] += a.y * bb.y; acc[1][2] += a.y * bb.z; acc[1][3] += a.y * bb.w;
            acc[2][0] += a.z * bb.x; acc[2][1] += a.z * bb.y; acc[2][2] += a.z * bb.z; acc[2][3] += a.z * bb.w;
            acc[3][0] += a.w * bb.x; acc[3][1] += a.w * bb.y; acc[3][2] += a.w * bb.z; acc[3][3] += a.w * bb.w;
        }
    }
#pragma unroll
    for (int i = 0; i < 4; i++) {
        int rl = ty * 4 + i;
        if (row0 + rl < cnt) {
            int tok = toks[rl];
            float4 o = make_float4(acc[i][0], acc[i][1], acc[i][2], acc[i][3]);
            *(float4*)(y + ((size_t)b * NN + tok) * DD + col0 + tx * 4) = o;
        }
    }
}

extern "C" void kernel_launch(void* const* d_in, const int* in_sizes, int n_in,
                              void* d_out, int out_size, void* d_ws, size_t ws_size,
                              hipStream_t stream) {
    const float* x       = (const float*)d_in[0];
    const float* gw      = (const float*)d_in[1];
    const float* experts = (const float*)d_in[2];
    float* y = (float*)d_out;

    char* ws = (char*)d_ws;
    float* gates    = (float*)(ws + OFF_GATES);
    float* topk_val = (float*)(ws + OFF_TOPK);
    int*   win      = (int*)(ws + OFF_WIN);
    int*   counts   = (int*)(ws + OFF_COUNTS);
    int*   lists    = (int*)(ws + OFF_LISTS);
    bool big = ws_size >= WS_NEEDED;
    unsigned short* xbf  = big ? (unsigned short*)(ws + OFF_XBF)  : nullptr;
    unsigned short* expt = big ? (unsigned short*)(ws + OFF_EXPT) : nullptr;

    init_kernel<<<64, 256, 0, stream>>>(win, counts);
    gate_logits_kernel<<<BN / 4, 256, 0, stream>>>(x, gw, gates, xbf);
    if (big) conv_experts_kernel<<<dim3(32, 32, 8), 256, 0, stream>>>(experts, expt);
    sinkhorn_kernel<<<BB, 1024, 0, stream>>>(gates);
    topk_kernel<<<BB * EE, 1024, 0, stream>>>(gates, topk_val, win);
    build_lists_kernel<<<BN / 256, 256, 0, stream>>>(topk_val, win, counts, lists);
    zero_inactive_kernel<<<BN, 256, 0, stream>>>(win, y);
    if (big)
        expert_gemm_mfma<<<dim3(8, 4, BB * EE), 256, 0, stream>>>(xbf, expt, counts, lists, y);
    else
        expert_gemm_kernel<<<dim3(16, 8, BB * EE), 256, 0, stream>>>(x, experts, counts, lists, y);
}

// Round 3
// 378.611 us; speedup vs baseline: 1.4856x; 1.0608x over previous
//
#include <hip/hip_runtime.h>
#include <hip/hip_bf16.h>
#include <stdint.h>

#define BB 4
#define NN 4096
#define DD 1024
#define EE 8
#define MM 512
#define BN (BB*NN)   // 16384

#define SBLK 32      // sinkhorn blocks total
#define SPB  8       // slices per batch
#define SROWS 512    // rows per slice

typedef __bf16 bf16x8 __attribute__((ext_vector_type(8)));
typedef float  floatx4 __attribute__((ext_vector_type(4)));

typedef const __attribute__((address_space(1))) void* gptr_t;
typedef __attribute__((address_space(3))) void* lptr_t;

__device__ __forceinline__ unsigned short f2bf(float f) {
    union { float f; unsigned u; } v; v.f = f;
    unsigned r = v.u + 0x7fffu + ((v.u >> 16) & 1u);   // round-to-nearest-even
    return (unsigned short)(r >> 16);
}

// ---------------- ws layout (bytes) ----------------
#define OFF_GATES   0u
#define OFF_TOPK    524288u
#define OFF_WIN     589824u
#define OFF_COUNTS  655360u
#define OFF_LISTS   655616u
#define OFF_BAR     721152u                        // 2 uints (pad 256)
#define OFF_PART    721408u                        // 32*16 floats = 2048 (pad 4096)
#define OFF_XBF     725504u                        // BN*DD*2 = 33554432
#define OFF_EXPT    (OFF_XBF + 33554432u)          // EE*DD*DD*2 = 16777216
#define WS_NEEDED   (OFF_EXPT + 16777216u)

__global__ __launch_bounds__(256) void init_kernel(int* __restrict__ win, int* __restrict__ counts,
                                                   unsigned* __restrict__ bar) {
    int i = blockIdx.x * 256 + threadIdx.x;
    if (i < BN) win[i] = -1;
    if (i < 32) counts[i] = 0;
    if (i < 2)  bar[i] = 0u;
}

// one wave per token: logits = x[tok] . gate_w[:,e]; also emit x in bf16
__global__ __launch_bounds__(256) void gate_logits_kernel(const float* __restrict__ x,
                                                          const float* __restrict__ gw,
                                                          float* __restrict__ tmat,
                                                          unsigned short* __restrict__ xbf) {
    __shared__ float gwT[EE][DD];   // transposed
    int tid = threadIdx.x;
    for (int i = tid; i < DD * EE; i += 256) {
        int k = i >> 3, e = i & 7;
        gwT[e][k] = gw[i];
    }
    __syncthreads();
    int wave = tid >> 6, lane = tid & 63;
    int t = blockIdx.x * 4 + wave;           // global token 0..16383
    const float4* xr = (const float4*)(x + (size_t)t * DD);
    ushort4* xo = xbf ? (ushort4*)(xbf + (size_t)t * DD) : nullptr;
    float acc[EE];
#pragma unroll
    for (int e = 0; e < EE; e++) acc[e] = 0.f;
#pragma unroll
    for (int jj = 0; jj < 4; jj++) {
        int k4 = jj * 64 + lane;             // float4 chunk index 0..255
        float4 v = xr[k4];
        if (xo) {
            ushort4 o; o.x = f2bf(v.x); o.y = f2bf(v.y); o.z = f2bf(v.z); o.w = f2bf(v.w);
            xo[k4] = o;
        }
        int k = k4 * 4;
#pragma unroll
        for (int e = 0; e < EE; e++)
            acc[e] += v.x * gwT[e][k] + v.y * gwT[e][k + 1] + v.z * gwT[e][k + 2] + v.w * gwT[e][k + 3];
    }
#pragma unroll
    for (int e = 0; e < EE; e++) {
        float v = acc[e];
        for (int off = 32; off > 0; off >>= 1) v += __shfl_down(v, off, 64);
        if (lane == 0) tmat[(size_t)t * EE + e] = logf(fmaxf(v, 1e-6f));
    }
}

// experts[e][k][col] fp32 -> expt[e][col][k] bf16 (transposed)
__global__ __launch_bounds__(256) void conv_experts_kernel(const float* __restrict__ E,
                                                           unsigned short* __restrict__ expt) {
    __shared__ float tile[32][33];
    int e = blockIdx.z, k0 = blockIdx.x * 32, c0 = blockIdx.y * 32;
    int tid = threadIdx.x;
    int r = tid >> 3, c4 = (tid & 7) * 4;
    float4 v = *(const float4*)(E + ((size_t)e * DD + k0 + r) * DD + c0 + c4);
    tile[r][c4 + 0] = v.x; tile[r][c4 + 1] = v.y; tile[r][c4 + 2] = v.z; tile[r][c4 + 3] = v.w;
    __syncthreads();
    int cc = tid >> 3, k4 = (tid & 7) * 4;
    ushort4 o;
    o.x = f2bf(tile[k4 + 0][cc]); o.y = f2bf(tile[k4 + 1][cc]);
    o.z = f2bf(tile[k4 + 2][cc]); o.w = f2bf(tile[k4 + 3][cc]);
    *(ushort4*)&expt[((size_t)e * DD + c0 + cc) * DD + k0 + k4] = o;
}

// device-scope grid barrier (sense via generation counter). bar[0]=cnt, bar[1]=gen.
__device__ __forceinline__ void grid_barrier(unsigned* bar, unsigned nblk) {
    __syncthreads();
    if (threadIdx.x == 0) {
        unsigned gen = __hip_atomic_load(bar + 1, __ATOMIC_RELAXED, __HIP_MEMORY_SCOPE_AGENT);
        unsigned arrived = __hip_atomic_fetch_add(bar, 1u, __ATOMIC_ACQ_REL, __HIP_MEMORY_SCOPE_AGENT) + 1u;
        if (arrived == nblk) {
            __hip_atomic_store(bar, 0u, __ATOMIC_RELAXED, __HIP_MEMORY_SCOPE_AGENT);
            __hip_atomic_fetch_add(bar + 1, 1u, __ATOMIC_RELEASE, __HIP_MEMORY_SCOPE_AGENT);
        } else {
            while (__hip_atomic_load(bar + 1, __ATOMIC_ACQUIRE, __HIP_MEMORY_SCOPE_AGENT) == gen)
                __builtin_amdgcn_s_sleep(2);
        }
    }
    __syncthreads();
}

// 32 blocks (8 per batch, 512 rows each, 1 row/thread), 8 sinkhorn iterations,
// one grid barrier per iteration (online-softmax partial combine for column LSE)
__global__ __launch_bounds__(512) void sinkhorn_mb(float* __restrict__ tmat,
                                                   float* __restrict__ part,
                                                   unsigned* __restrict__ bar) {
    int g = blockIdx.x;
    int b = g >> 3, sl = g & 7;
    int tid = threadIdx.x;
    int wave = tid >> 6, lane = tid & 63;
    int row = sl * SROWS + tid;
    float* tr = tmat + ((size_t)b * NN + row) * EE;
    float tv[EE];
#pragma unroll
    for (int e = 0; e < EE; e++) tv[e] = tr[e];

    __shared__ float red[8][8];    // [wave][expert]
    __shared__ float bcm[8];       // block/col combine buffer

    float* pm = part + (size_t)(b * SPB + sl) * 16;   // [0..7]=m, [8..15]=s

    for (int it = 0; it < 8; it++) {
        // ---- block-local column max ----
        float cm[EE];
#pragma unroll
        for (int e = 0; e < EE; e++) {
            float m = tv[e];
            for (int off = 32; off > 0; off >>= 1) m = fmaxf(m, __shfl_down(m, off, 64));
            cm[e] = m;
        }
        if (lane == 0) {
#pragma unroll
            for (int e = 0; e < EE; e++) red[wave][e] = cm[e];
        }
        __syncthreads();
        if (tid < 8) {
            float m = red[0][tid];
#pragma unroll
            for (int w = 1; w < 8; w++) m = fmaxf(m, red[w][tid]);
            bcm[tid] = m;
        }
        __syncthreads();
        float bm[EE];
#pragma unroll
        for (int e = 0; e < EE; e++) bm[e] = bcm[e];
        __syncthreads();
        // ---- block-local column sumexp ----
        float cs[EE];
#pragma unroll
        for (int e = 0; e < EE; e++) {
            float s = expf(tv[e] - bm[e]);
            for (int off = 32; off > 0; off >>= 1) s += __shfl_down(s, off, 64);
            cs[e] = s;
        }
        if (lane == 0) {
#pragma unroll
            for (int e = 0; e < EE; e++) red[wave][e] = cs[e];
        }
        __syncthreads();
        if (tid < 8) {
            float s = 0.f;
#pragma unroll
            for (int w = 0; w < 8; w++) s += red[w][tid];
            // publish partials device-scope
            __hip_atomic_store(&pm[tid], bm[tid], __ATOMIC_RELAXED, __HIP_MEMORY_SCOPE_AGENT);
            __hip_atomic_store(&pm[8 + tid], s,   __ATOMIC_RELAXED, __HIP_MEMORY_SCOPE_AGENT);
        }
        grid_barrier(bar, SBLK);
        // ---- combine partials -> column LSE ----
        if (tid < 8) {
            const float* pb = part + (size_t)b * SPB * 16;
            float ms[SPB], ss[SPB];
#pragma unroll
            for (int p = 0; p < SPB; p++) {
                ms[p] = __hip_atomic_load(&pb[p * 16 + tid],     __ATOMIC_RELAXED, __HIP_MEMORY_SCOPE_AGENT);
                ss[p] = __hip_atomic_load(&pb[p * 16 + 8 + tid], __ATOMIC_RELAXED, __HIP_MEMORY_SCOPE_AGENT);
            }
            float m = ms[0];
#pragma unroll
            for (int p = 1; p < SPB; p++) m = fmaxf(m, ms[p]);
            float stot = 0.f;
#pragma unroll
            for (int p = 0; p < SPB; p++) stot += ss[p] * expf(ms[p] - m);
            bcm[tid] = m + logf(stot);
        }
        __syncthreads();
#pragma unroll
        for (int e = 0; e < EE; e++) tv[e] -= bcm[e];
        // ---- row LSE (thread-local) ----
        {
            float m = tv[0];
#pragma unroll
            for (int e = 1; e < EE; e++) m = fmaxf(m, tv[e]);
            float s = 0.f;
#pragma unroll
            for (int e = 0; e < EE; e++) s += expf(tv[e] - m);
            float lse = m + logf(s);
#pragma unroll
            for (int e = 0; e < EE; e++) tv[e] -= lse;
        }
        __syncthreads();   // red/bcm reuse protection for next iteration
    }
#pragma unroll
    for (int e = 0; e < EE; e++) tr[e] = expf(tv[e]);
}

// one block per (b,e): full bitonic sort (desc, stable) of 4096 gates
__global__ __launch_bounds__(1024) void topk_kernel(const float* __restrict__ gates,
                                                    float* __restrict__ topk_val,
                                                    int* __restrict__ win) {
    __shared__ unsigned long long key[NN];
    int be = blockIdx.x;
    int b = be >> 3, e = be & 7;
    int tid = threadIdx.x;
    const float* gb = gates + (size_t)b * NN * EE + e;
    for (int t = tid; t < NN; t += 1024) {
        float g = gb[(size_t)t * EE];     // g in (0,1]: uint order == float order
        unsigned int fb = __float_as_uint(g);
        key[t] = ((unsigned long long)fb << 32) | (unsigned int)(~t);
    }
    for (unsigned k = 2; k <= (unsigned)NN; k <<= 1) {
        for (unsigned j = k >> 1; j > 0; j >>= 1) {
            __syncthreads();
            for (unsigned i = tid; i < (unsigned)NN; i += 1024) {
                unsigned l = i ^ j;
                if (l > i) {
                    unsigned long long a = key[i], c = key[l];
                    bool up = ((i & k) == 0);
                    if (up ? (a < c) : (a > c)) { key[i] = c; key[l] = a; }
                }
            }
        }
    }
    __syncthreads();
    if (tid < MM) {
        unsigned long long kk = key[tid];
        float v = __uint_as_float((unsigned int)(kk >> 32));
        int tok = (int)(~(unsigned int)kk);
        topk_val[be * MM + tid] = v;
        // numpy scatter: last write in C-order over (m,e) wins -> max code wins
        atomicMax(&win[b * NN + tok], tid * 8 + e);
    }
}

__global__ __launch_bounds__(256) void build_lists_kernel(const float* __restrict__ topk_val,
                                                          int* __restrict__ win,
                                                          int* __restrict__ counts,
                                                          int* __restrict__ lists) {
    int i = blockIdx.x * 256 + threadIdx.x;
    if (i >= BN) return;
    int b = i >> 12, tok = i & 4095;
    int w = win[i];
    int active = 0;
    if (w >= 0) {
        int m = w >> 3, e = w & 7;
        float gv = topk_val[(b * 8 + e) * MM + m];
        if (gv > 0.5f) {
            int p = atomicAdd(&counts[b * 8 + e], 1);
            lists[(b * 8 + e) * MM + p] = tok;
            active = 1;
        }
    }
    win[i] = active;
}

__global__ __launch_bounds__(256) void zero_inactive_kernel(const int* __restrict__ act,
                                                            float* __restrict__ y) {
    int t = blockIdx.x;
    if (act[t]) return;
    float4* row = (float4*)(y + (size_t)t * DD);
    row[threadIdx.x] = make_float4(0.f, 0.f, 0.f, 0.f);
}

// ---------- bf16 MFMA gathered GEMM: y[b,tok,:] = xbf[b,tok,:] @ expt[e]^T ----------
__global__ __launch_bounds__(256) void expert_gemm_mfma(const unsigned short* __restrict__ xbf,
                                                        const unsigned short* __restrict__ expt,
                                                        const int* __restrict__ counts,
                                                        const int* __restrict__ lists,
                                                        float* __restrict__ y) {
    int be = blockIdx.z;
    int b = be >> 3, e = be & 7;
    int cnt = counts[be];
    int row0 = blockIdx.y * 128;
    if (row0 >= cnt) return;
    int col0 = blockIdx.x * 128;

    __shared__ unsigned short As[128 * 32];   // [row][k]  8 KB
    __shared__ unsigned short Bs[128 * 32];   // [col][k]  8 KB
    __shared__ int toks[128];

    int tid = threadIdx.x;
    int wave = tid >> 6, lane = tid & 63;
    int m16 = lane & 15, quad = lane >> 4;
    int wave_m = wave >> 1, wave_n = wave & 1;

    if (tid < 128) {
        int r = row0 + tid;
        toks[tid] = lists[be * MM + (r < cnt ? r : cnt - 1)];
    }

    int r0 = tid >> 2;          // 0..63 (staging row/col)
    int ch = tid & 3;           // 16B chunk (8 bf16)

    const unsigned short* xb = xbf + (size_t)b * NN * DD;
    const unsigned short* Eb = expt + (size_t)e * DD * DD;

    floatx4 acc[4][4];
#pragma unroll
    for (int i = 0; i < 4; i++)
#pragma unroll
        for (int j = 0; j < 4; j++) acc[i][j] = (floatx4)0.f;

    for (int k0 = 0; k0 < DD; k0 += 32) {
        __syncthreads();
        {
            const unsigned short* gA0 = xb + (size_t)toks[r0] * DD + k0 + ch * 8;
            const unsigned short* gA1 = xb + (size_t)toks[64 + r0] * DD + k0 + ch * 8;
            const unsigned short* gB0 = Eb + (size_t)(col0 + r0) * DD + k0 + ch * 8;
            const unsigned short* gB1 = Eb + (size_t)(col0 + 64 + r0) * DD + k0 + ch * 8;
            __builtin_amdgcn_global_load_lds((gptr_t)gA0, (lptr_t)(As + (size_t)tid * 8), 16, 0, 0);
            __builtin_amdgcn_global_load_lds((gptr_t)gA1, (lptr_t)(As + 64 * 32 + (size_t)tid * 8), 16, 0, 0);
            __builtin_amdgcn_global_load_lds((gptr_t)gB0, (lptr_t)(Bs + (size_t)tid * 8), 16, 0, 0);
            __builtin_amdgcn_global_load_lds((gptr_t)gB1, (lptr_t)(Bs + 64 * 32 + (size_t)tid * 8), 16, 0, 0);
        }
        __syncthreads();
        bf16x8 af[4], bfr[4];
#pragma unroll
        for (int i = 0; i < 4; i++)
            af[i] = *(const bf16x8*)&As[(wave_m * 64 + i * 16 + m16) * 32 + quad * 8];
#pragma unroll
        for (int j = 0; j < 4; j++)
            bfr[j] = *(const bf16x8*)&Bs[(wave_n * 64 + j * 16 + m16) * 32 + quad * 8];
#pragma unroll
        for (int i = 0; i < 4; i++)
#pragma unroll
            for (int j = 0; j < 4; j++)
                acc[i][j] = __builtin_amdgcn_mfma_f32_16x16x32_bf16(af[i], bfr[j], acc[i][j], 0, 0, 0);
    }

#pragma unroll
    for (int i = 0; i < 4; i++) {
#pragma unroll
        for (int r = 0; r < 4; r++) {
            int lr = wave_m * 64 + i * 16 + quad * 4 + r;
            if (row0 + lr < cnt) {
                int tok = toks[lr];
                float* yr = y + ((size_t)b * NN + tok) * DD + col0 + wave_n * 64 + m16;
#pragma unroll
                for (int j = 0; j < 4; j++) yr[j * 16] = acc[i][j][r];
            }
        }
    }
}

// fallback fp32 GEMM (used only if ws too small for bf16 buffers)
__global__ __launch_bounds__(256) void expert_gemm_kernel(const float* __restrict__ x,
                                                          const float* __restrict__ experts,
                                                          const int* __restrict__ counts,
                                                          const int* __restrict__ lists,
                                                          float* __restrict__ y) {
    int be = blockIdx.z;
    int b = be >> 3, e = be & 7;
    int cnt = counts[be];
    int row0 = blockIdx.y * 64;
    if (row0 >= cnt) return;
    int col0 = blockIdx.x * 64;
    __shared__ float As[16][68];
    __shared__ float Bs[16][68];
    __shared__ int toks[64];
    int tid = threadIdx.x;
    if (tid < 64) {
        int r = row0 + tid;
        toks[tid] = (r < cnt) ? lists[be * MM + r] : -1;
    }
    __syncthreads();
    int tx = tid & 15, ty = tid >> 4;
    int ar = tid >> 2;
    int ak = (tid & 3) * 4;
    int bk = tid >> 4;
    int bc4 = (tid & 15) * 4;
    int atok = toks[ar];
    const float* xb = x + (size_t)b * NN * DD;
    const float* Eb = experts + (size_t)e * DD * DD + col0;
    float acc[4][4] = {};
    for (int k0 = 0; k0 < DD; k0 += 16) {
        float4 av;
        if (atok >= 0) av = *(const float4*)(xb + (size_t)atok * DD + k0 + ak);
        else av = make_float4(0.f, 0.f, 0.f, 0.f);
        float4 bv = *(const float4*)(Eb + (size_t)(k0 + bk) * DD + bc4);
        __syncthreads();
        As[ak + 0][ar] = av.x; As[ak + 1][ar] = av.y; As[ak + 2][ar] = av.z; As[ak + 3][ar] = av.w;
        *(float4*)&Bs[bk][bc4] = bv;
        __syncthreads();
#pragma unroll
        for (int kk = 0; kk < 16; kk++) {
            float4 a = *(const float4*)&As[kk][ty * 4];
            float4 bb = *(const float4*)&Bs[kk][tx * 4];
            acc[0][0] += a.x * bb.x; acc[0][1] += a.x * bb.y; acc[0][2] += a.x * bb.z; acc[0][3] += a.x * bb.w;
            acc[1][0] += a.y * bb.x; acc[1][1] += a.y * bb.y; acc[1][2] += a.y * bb.z; acc[1][3] += a.y * bb.w;
            acc[2][0] += a.z * bb.x; acc[2][1] += a.z * bb.y; acc[2][2] += a.z * bb.z; acc[2][3] += a.z * bb.w;
            acc[3][0] += a.w * bb.x; acc[3][1] += a.w * bb.y; acc[3][2] += a.w * bb.z; acc[3][3] += a.w * bb.w;
        }
    }
#pragma unroll
    for (int i = 0; i < 4; i++) {
        int rl = ty * 4 + i;
        if (row0 + rl < cnt) {
            int tok = toks[rl];
            float4 o = make_float4(acc[i][0], acc[i][1], acc[i][2], acc[i][3]);
            *(float4*)(y + ((size_t)b * NN + tok) * DD + col0 + tx * 4) = o;
        }
    }
}

extern "C" void kernel_launch(void* const* d_in, const int* in_sizes, int n_in,
                              void* d_out, int out_size, void* d_ws, size_t ws_size,
                              hipStream_t stream) {
    const float* x       = (const float*)d_in[0];
    const float* gw      = (const float*)d_in[1];
    const float* experts = (const float*)d_in[2];
    float* y = (float*)d_out;

    char* ws = (char*)d_ws;
    float*    gates    = (float*)(ws + OFF_GATES);
    float*    topk_val = (float*)(ws + OFF_TOPK);
    int*      win      = (int*)(ws + OFF_WIN);
    int*      counts   = (int*)(ws + OFF_COUNTS);
    int*      lists    = (int*)(ws + OFF_LISTS);
    unsigned* bar      = (unsigned*)(ws + OFF_BAR);
    float*    part     = (float*)(ws + OFF_PART);
    bool big = ws_size >= WS_NEEDED;
    unsigned short* xbf  = big ? (unsigned short*)(ws + OFF_XBF)  : nullptr;
    unsigned short* expt = big ? (unsigned short*)(ws + OFF_EXPT) : nullptr;

    init_kernel<<<64, 256, 0, stream>>>(win, counts, bar);
    gate_logits_kernel<<<BN / 4, 256, 0, stream>>>(x, gw, gates, xbf);
    if (big) conv_experts_kernel<<<dim3(32, 32, 8), 256, 0, stream>>>(experts, expt);
    sinkhorn_mb<<<SBLK, 512, 0, stream>>>(gates, part, bar);
    topk_kernel<<<BB * EE, 1024, 0, stream>>>(gates, topk_val, win);
    build_lists_kernel<<<BN / 256, 256, 0, stream>>>(topk_val, win, counts, lists);
    zero_inactive_kernel<<<BN, 256, 0, stream>>>(win, y);
    if (big)
        expert_gemm_mfma<<<dim3(8, 4, BB * EE), 256, 0, stream>>>(xbf, expt, counts, lists, y);
    else
        expert_gemm_kernel<<<dim3(16, 8, BB * EE), 256, 0, stream>>>(x, experts, counts, lists, y);
}

// Round 4
// 366.180 us; speedup vs baseline: 1.5360x; 1.0339x over previous
//
#include <hip/hip_runtime.h>
#include <hip/hip_bf16.h>
#include <stdint.h>

#define BB 4
#define NN 4096
#define DD 1024
#define EE 8
#define MM 512
#define BN (BB*NN)   // 16384

#define SBLK 32      // sinkhorn blocks total
#define SPB  8       // slices per batch
#define SROWS 512    // rows per slice

typedef __bf16 bf16x8 __attribute__((ext_vector_type(8)));
typedef float  floatx4 __attribute__((ext_vector_type(4)));

typedef const __attribute__((address_space(1))) void* gptr_t;
typedef __attribute__((address_space(3))) void* lptr_t;

__device__ __forceinline__ unsigned short f2bf(float f) {
    union { float f; unsigned u; } v; v.f = f;
    unsigned r = v.u + 0x7fffu + ((v.u >> 16) & 1u);   // round-to-nearest-even
    return (unsigned short)(r >> 16);
}

// ---------------- ws layout (bytes) ----------------
#define OFF_GATES   0u                             // logits, 524288
#define OFF_TOPK    524288u                        // 65536
#define OFF_WIN     589824u                        // 65536
#define OFF_COUNTS  655360u                        // 256
#define OFF_LISTS   655616u                        // 65536
#define OFF_BAR     721152u                        // 256
#define OFF_PART    721408u                        // 4096
#define OFF_KEYS    725504u                        // 32*4096*8 = 1048576
#define OFF_XBF     1774080u                       // BN*DD*2 = 33554432
#define OFF_EXPT    35328512u                      // EE*DD*DD*2 = 16777216
#define WS_NEEDED   52105728u

__global__ __launch_bounds__(256) void init_kernel(int* __restrict__ win, int* __restrict__ counts,
                                                   unsigned* __restrict__ bar) {
    int i = blockIdx.x * 256 + threadIdx.x;
    if (i < BN) win[i] = -1;
    if (i < 32) counts[i] = 0;
    if (i < 2)  bar[i] = 0u;
}

// gw held fully in per-lane registers; 8 tokens per wave; also emits x in bf16.
// grid 512 blocks x 256 thr. lane's k-slice: k = j*256 + lane*4 + r (j,r in 0..3)
__global__ __launch_bounds__(256) void gate_logits_kernel(const float* __restrict__ x,
                                                          const float* __restrict__ gw,
                                                          float* __restrict__ tmat,
                                                          unsigned short* __restrict__ xbf) {
    int tid = threadIdx.x;
    int wave = tid >> 6, lane = tid & 63;
    float4 g0[4][4], g1[4][4];     // [j][r]: experts 0..3 / 4..7 for row j*256+lane*4+r
#pragma unroll
    for (int j = 0; j < 4; j++)
#pragma unroll
        for (int r = 0; r < 4; r++) {
            const float4* p = (const float4*)(gw + (size_t)(j * 256 + lane * 4 + r) * 8);
            g0[j][r] = p[0];
            g1[j][r] = p[1];
        }
    int tok0 = (blockIdx.x * 4 + wave) * 8;
    for (int tt = 0; tt < 8; tt++) {
        int tok = tok0 + tt;
        const float4* xr = (const float4*)(x + (size_t)tok * DD);
        float4 a03 = make_float4(0.f, 0.f, 0.f, 0.f);
        float4 a47 = make_float4(0.f, 0.f, 0.f, 0.f);
#pragma unroll
        for (int j = 0; j < 4; j++) {
            float4 xv = xr[j * 64 + lane];
            if (xbf) {
                ushort4 o; o.x = f2bf(xv.x); o.y = f2bf(xv.y); o.z = f2bf(xv.z); o.w = f2bf(xv.w);
                ((ushort4*)(xbf + (size_t)tok * DD))[j * 64 + lane] = o;
            }
            a03.x += xv.x * g0[j][0].x + xv.y * g0[j][1].x + xv.z * g0[j][2].x + xv.w * g0[j][3].x;
            a03.y += xv.x * g0[j][0].y + xv.y * g0[j][1].y + xv.z * g0[j][2].y + xv.w * g0[j][3].y;
            a03.z += xv.x * g0[j][0].z + xv.y * g0[j][1].z + xv.z * g0[j][2].z + xv.w * g0[j][3].z;
            a03.w += xv.x * g0[j][0].w + xv.y * g0[j][1].w + xv.z * g0[j][2].w + xv.w * g0[j][3].w;
            a47.x += xv.x * g1[j][0].x + xv.y * g1[j][1].x + xv.z * g1[j][2].x + xv.w * g1[j][3].x;
            a47.y += xv.x * g1[j][0].y + xv.y * g1[j][1].y + xv.z * g1[j][2].y + xv.w * g1[j][3].y;
            a47.z += xv.x * g1[j][0].z + xv.y * g1[j][1].z + xv.z * g1[j][2].z + xv.w * g1[j][3].z;
            a47.w += xv.x * g1[j][0].w + xv.y * g1[j][1].w + xv.z * g1[j][2].w + xv.w * g1[j][3].w;
        }
        float acc[8] = {a03.x, a03.y, a03.z, a03.w, a47.x, a47.y, a47.z, a47.w};
#pragma unroll
        for (int e = 0; e < EE; e++) {
            float v = acc[e];
            for (int off = 32; off > 0; off >>= 1) v += __shfl_down(v, off, 64);
            if (lane == 0) tmat[(size_t)tok * EE + e] = logf(fmaxf(v, 1e-6f));
        }
    }
}

// experts[e][k][col] fp32 -> expt[e][col][k] bf16 (transposed)
__global__ __launch_bounds__(256) void conv_experts_kernel(const float* __restrict__ E,
                                                           unsigned short* __restrict__ expt) {
    __shared__ float tile[32][33];
    int e = blockIdx.z, k0 = blockIdx.x * 32, c0 = blockIdx.y * 32;
    int tid = threadIdx.x;
    int r = tid >> 3, c4 = (tid & 7) * 4;
    float4 v = *(const float4*)(E + ((size_t)e * DD + k0 + r) * DD + c0 + c4);
    tile[r][c4 + 0] = v.x; tile[r][c4 + 1] = v.y; tile[r][c4 + 2] = v.z; tile[r][c4 + 3] = v.w;
    __syncthreads();
    int cc = tid >> 3, k4 = (tid & 7) * 4;
    ushort4 o;
    o.x = f2bf(tile[k4 + 0][cc]); o.y = f2bf(tile[k4 + 1][cc]);
    o.z = f2bf(tile[k4 + 2][cc]); o.w = f2bf(tile[k4 + 3][cc]);
    *(ushort4*)&expt[((size_t)e * DD + c0 + cc) * DD + k0 + k4] = o;
}

// device-scope grid barrier. bar[0]=cnt, bar[1]=gen.
__device__ __forceinline__ void grid_barrier(unsigned* bar, unsigned nblk) {
    __syncthreads();
    if (threadIdx.x == 0) {
        unsigned gen = __hip_atomic_load(bar + 1, __ATOMIC_RELAXED, __HIP_MEMORY_SCOPE_AGENT);
        unsigned arrived = __hip_atomic_fetch_add(bar, 1u, __ATOMIC_ACQ_REL, __HIP_MEMORY_SCOPE_AGENT) + 1u;
        if (arrived == nblk) {
            __hip_atomic_store(bar, 0u, __ATOMIC_RELAXED, __HIP_MEMORY_SCOPE_AGENT);
            __hip_atomic_fetch_add(bar + 1, 1u, __ATOMIC_RELEASE, __HIP_MEMORY_SCOPE_AGENT);
        } else {
            while (__hip_atomic_load(bar + 1, __ATOMIC_ACQUIRE, __HIP_MEMORY_SCOPE_AGENT) == gen)
                __builtin_amdgcn_s_sleep(2);
        }
    }
    __syncthreads();
}

// 32 blocks (8/batch, 512 rows each, 1 row/thread), 8 iterations, 1 grid barrier each.
// Final output: 64-bit sort keys per (b,e) column (fbits<<32 | ~row).
__global__ __launch_bounds__(512) void sinkhorn_mb(float* __restrict__ tmat,
                                                   float* __restrict__ part,
                                                   unsigned* __restrict__ bar,
                                                   unsigned long long* __restrict__ keys) {
    int g = blockIdx.x;
    int b = g >> 3, sl = g & 7;
    int tid = threadIdx.x;
    int wave = tid >> 6, lane = tid & 63;
    int row = sl * SROWS + tid;
    float* tr = tmat + ((size_t)b * NN + row) * EE;
    float tv[EE];
#pragma unroll
    for (int e = 0; e < EE; e++) tv[e] = tr[e];

    __shared__ float red[8][8];
    __shared__ float bcm[8];

    float* pm = part + (size_t)(b * SPB + sl) * 16;   // [0..7]=m, [8..15]=s

    for (int it = 0; it < 8; it++) {
        float cm[EE];
#pragma unroll
        for (int e = 0; e < EE; e++) {
            float m = tv[e];
            for (int off = 32; off > 0; off >>= 1) m = fmaxf(m, __shfl_down(m, off, 64));
            cm[e] = m;
        }
        if (lane == 0) {
#pragma unroll
            for (int e = 0; e < EE; e++) red[wave][e] = cm[e];
        }
        __syncthreads();
        if (tid < 8) {
            float m = red[0][tid];
#pragma unroll
            for (int w = 1; w < 8; w++) m = fmaxf(m, red[w][tid]);
            bcm[tid] = m;
        }
        __syncthreads();
        float bm[EE];
#pragma unroll
        for (int e = 0; e < EE; e++) bm[e] = bcm[e];
        __syncthreads();
        float cs[EE];
#pragma unroll
        for (int e = 0; e < EE; e++) {
            float s = expf(tv[e] - bm[e]);
            for (int off = 32; off > 0; off >>= 1) s += __shfl_down(s, off, 64);
            cs[e] = s;
        }
        if (lane == 0) {
#pragma unroll
            for (int e = 0; e < EE; e++) red[wave][e] = cs[e];
        }
        __syncthreads();
        if (tid < 8) {
            float s = 0.f;
#pragma unroll
            for (int w = 0; w < 8; w++) s += red[w][tid];
            __hip_atomic_store(&pm[tid], bm[tid], __ATOMIC_RELAXED, __HIP_MEMORY_SCOPE_AGENT);
            __hip_atomic_store(&pm[8 + tid], s,   __ATOMIC_RELAXED, __HIP_MEMORY_SCOPE_AGENT);
        }
        grid_barrier(bar, SBLK);
        if (tid < 8) {
            const float* pb = part + (size_t)b * SPB * 16;
            float ms[SPB], ss[SPB];
#pragma unroll
            for (int p = 0; p < SPB; p++) {
                ms[p] = __hip_atomic_load(&pb[p * 16 + tid],     __ATOMIC_RELAXED, __HIP_MEMORY_SCOPE_AGENT);
                ss[p] = __hip_atomic_load(&pb[p * 16 + 8 + tid], __ATOMIC_RELAXED, __HIP_MEMORY_SCOPE_AGENT);
            }
            float m = ms[0];
#pragma unroll
            for (int p = 1; p < SPB; p++) m = fmaxf(m, ms[p]);
            float stot = 0.f;
#pragma unroll
            for (int p = 0; p < SPB; p++) stot += ss[p] * expf(ms[p] - m);
            bcm[tid] = m + logf(stot);
        }
        __syncthreads();
#pragma unroll
        for (int e = 0; e < EE; e++) tv[e] -= bcm[e];
        {
            float m = tv[0];
#pragma unroll
            for (int e = 1; e < EE; e++) m = fmaxf(m, tv[e]);
            float s = 0.f;
#pragma unroll
            for (int e = 0; e < EE; e++) s += expf(tv[e] - m);
            float lse = m + logf(s);
#pragma unroll
            for (int e = 0; e < EE; e++) tv[e] -= lse;
        }
        __syncthreads();
    }
    // emit sort keys: gates in (0,1] positive -> u32 float-bit order == value order
#pragma unroll
    for (int e = 0; e < EE; e++) {
        unsigned fb = __float_as_uint(expf(tv[e]));
        keys[(size_t)(b * EE + e) * NN + row] =
            ((unsigned long long)fb << 32) | (unsigned)(~row);
    }
}

// exact rank by counting: rank(t) = #{j: key_j > key_t}; selected iff rank < 512.
// grid (16 token-chunks, 32 columns), 256 thr; column cached in 32KB LDS.
__global__ __launch_bounds__(256) void rank_topk_kernel(const unsigned long long* __restrict__ keys,
                                                        float* __restrict__ topk_val,
                                                        int* __restrict__ win) {
    __shared__ unsigned long long K[NN];   // 32 KB
    int be = blockIdx.y;
    int b = be >> 3, e = be & 7;
    int tid = threadIdx.x;
    const unsigned long long* kcol = keys + (size_t)be * NN;
    for (int i = tid; i < NN / 2; i += 256)
        ((ulonglong2*)K)[i] = ((const ulonglong2*)kcol)[i];
    __syncthreads();
    int t = blockIdx.x * 256 + tid;
    unsigned long long my = K[t];
    int cnt = 0;
    for (int j = 0; j < NN; j += 8) {   // wave-uniform LDS reads -> broadcast, conflict-free
        ulonglong2 a = *(const ulonglong2*)&K[j + 0];
        ulonglong2 c = *(const ulonglong2*)&K[j + 2];
        ulonglong2 d = *(const ulonglong2*)&K[j + 4];
        ulonglong2 f = *(const ulonglong2*)&K[j + 6];
        cnt += (int)(a.x > my) + (int)(a.y > my) + (int)(c.x > my) + (int)(c.y > my)
             + (int)(d.x > my) + (int)(d.y > my) + (int)(f.x > my) + (int)(f.y > my);
    }
    if (cnt < MM) {
        topk_val[be * MM + cnt] = __uint_as_float((unsigned)(my >> 32));
        atomicMax(&win[b * NN + t], cnt * 8 + e);   // numpy scatter: max (m*8+e) wins
    }
}

__global__ __launch_bounds__(256) void build_lists_kernel(const float* __restrict__ topk_val,
                                                          int* __restrict__ win,
                                                          int* __restrict__ counts,
                                                          int* __restrict__ lists) {
    int i = blockIdx.x * 256 + threadIdx.x;
    if (i >= BN) return;
    int b = i >> 12, tok = i & 4095;
    int w = win[i];
    int active = 0;
    if (w >= 0) {
        int m = w >> 3, e = w & 7;
        float gv = topk_val[(b * 8 + e) * MM + m];
        if (gv > 0.5f) {
            int p = atomicAdd(&counts[b * 8 + e], 1);
            lists[(b * 8 + e) * MM + p] = tok;
            active = 1;
        }
    }
    win[i] = active;
}

__global__ __launch_bounds__(256) void zero_inactive_kernel(const int* __restrict__ act,
                                                            float* __restrict__ y) {
    int t = blockIdx.x;
    if (act[t]) return;
    float4* row = (float4*)(y + (size_t)t * DD);
    row[threadIdx.x] = make_float4(0.f, 0.f, 0.f, 0.f);
}

// ---------- bf16 MFMA gathered GEMM: y[b,tok,:] = xbf[b,tok,:] @ expt[e]^T ----------
__global__ __launch_bounds__(256) void expert_gemm_mfma(const unsigned short* __restrict__ xbf,
                                                        const unsigned short* __restrict__ expt,
                                                        const int* __restrict__ counts,
                                                        const int* __restrict__ lists,
                                                        float* __restrict__ y) {
    int be = blockIdx.z;
    int b = be >> 3, e = be & 7;
    int cnt = counts[be];
    int row0 = blockIdx.y * 128;
    if (row0 >= cnt) return;
    int col0 = blockIdx.x * 128;

    __shared__ unsigned short As[128 * 32];   // [row][k]
    __shared__ unsigned short Bs[128 * 32];   // [col][k]
    __shared__ int toks[128];

    int tid = threadIdx.x;
    int wave = tid >> 6, lane = tid & 63;
    int m16 = lane & 15, quad = lane >> 4;
    int wave_m = wave >> 1, wave_n = wave & 1;

    if (tid < 128) {
        int r = row0 + tid;
        toks[tid] = lists[be * MM + (r < cnt ? r : cnt - 1)];
    }

    int r0 = tid >> 2;
    int ch = tid & 3;

    const unsigned short* xb = xbf + (size_t)b * NN * DD;
    const unsigned short* Eb = expt + (size_t)e * DD * DD;

    floatx4 acc[4][4];
#pragma unroll
    for (int i = 0; i < 4; i++)
#pragma unroll
        for (int j = 0; j < 4; j++) acc[i][j] = (floatx4)0.f;

    for (int k0 = 0; k0 < DD; k0 += 32) {
        __syncthreads();
        {
            const unsigned short* gA0 = xb + (size_t)toks[r0] * DD + k0 + ch * 8;
            const unsigned short* gA1 = xb + (size_t)toks[64 + r0] * DD + k0 + ch * 8;
            const unsigned short* gB0 = Eb + (size_t)(col0 + r0) * DD + k0 + ch * 8;
            const unsigned short* gB1 = Eb + (size_t)(col0 + 64 + r0) * DD + k0 + ch * 8;
            __builtin_amdgcn_global_load_lds((gptr_t)gA0, (lptr_t)(As + (size_t)tid * 8), 16, 0, 0);
            __builtin_amdgcn_global_load_lds((gptr_t)gA1, (lptr_t)(As + 64 * 32 + (size_t)tid * 8), 16, 0, 0);
            __builtin_amdgcn_global_load_lds((gptr_t)gB0, (lptr_t)(Bs + (size_t)tid * 8), 16, 0, 0);
            __builtin_amdgcn_global_load_lds((gptr_t)gB1, (lptr_t)(Bs + 64 * 32 + (size_t)tid * 8), 16, 0, 0);
        }
        __syncthreads();
        bf16x8 af[4], bfr[4];
#pragma unroll
        for (int i = 0; i < 4; i++)
            af[i] = *(const bf16x8*)&As[(wave_m * 64 + i * 16 + m16) * 32 + quad * 8];
#pragma unroll
        for (int j = 0; j < 4; j++)
            bfr[j] = *(const bf16x8*)&Bs[(wave_n * 64 + j * 16 + m16) * 32 + quad * 8];
#pragma unroll
        for (int i = 0; i < 4; i++)
#pragma unroll
            for (int j = 0; j < 4; j++)
                acc[i][j] = __builtin_amdgcn_mfma_f32_16x16x32_bf16(af[i], bfr[j], acc[i][j], 0, 0, 0);
    }

#pragma unroll
    for (int i = 0; i < 4; i++) {
#pragma unroll
        for (int r = 0; r < 4; r++) {
            int lr = wave_m * 64 + i * 16 + quad * 4 + r;
            if (row0 + lr < cnt) {
                int tok = toks[lr];
                float* yr = y + ((size_t)b * NN + tok) * DD + col0 + wave_n * 64 + m16;
#pragma unroll
                for (int j = 0; j < 4; j++) yr[j * 16] = acc[i][j][r];
            }
        }
    }
}

// fallback fp32 GEMM (ws too small for bf16 buffers)
__global__ __launch_bounds__(256) void expert_gemm_kernel(const float* __restrict__ x,
                                                          const float* __restrict__ experts,
                                                          const int* __restrict__ counts,
                                                          const int* __restrict__ lists,
                                                          float* __restrict__ y) {
    int be = blockIdx.z;
    int b = be >> 3, e = be & 7;
    int cnt = counts[be];
    int row0 = blockIdx.y * 64;
    if (row0 >= cnt) return;
    int col0 = blockIdx.x * 64;
    __shared__ float As[16][68];
    __shared__ float Bs[16][68];
    __shared__ int toks[64];
    int tid = threadIdx.x;
    if (tid < 64) {
        int r = row0 + tid;
        toks[tid] = (r < cnt) ? lists[be * MM + r] : -1;
    }
    __syncthreads();
    int tx = tid & 15, ty = tid >> 4;
    int ar = tid >> 2;
    int ak = (tid & 3) * 4;
    int bk = tid >> 4;
    int bc4 = (tid & 15) * 4;
    int atok = toks[ar];
    const float* xb = x + (size_t)b * NN * DD;
    const float* Eb = experts + (size_t)e * DD * DD + col0;
    float acc[4][4] = {};
    for (int k0 = 0; k0 < DD; k0 += 16) {
        float4 av;
        if (atok >= 0) av = *(const float4*)(xb + (size_t)atok * DD + k0 + ak);
        else av = make_float4(0.f, 0.f, 0.f, 0.f);
        float4 bv = *(const float4*)(Eb + (size_t)(k0 + bk) * DD + bc4);
        __syncthreads();
        As[ak + 0][ar] = av.x; As[ak + 1][ar] = av.y; As[ak + 2][ar] = av.z; As[ak + 3][ar] = av.w;
        *(float4*)&Bs[bk][bc4] = bv;
        __syncthreads();
#pragma unroll
        for (int kk = 0; kk < 16; kk++) {
            float4 a = *(const float4*)&As[kk][ty * 4];
            float4 bb = *(const float4*)&Bs[kk][tx * 4];
            acc[0][0] += a.x * bb.x; acc[0][1] += a.x * bb.y; acc[0][2] += a.x * bb.z; acc[0][3] += a.x * bb.w;
            acc[1][0] += a.y * bb.x; acc[1][1] += a.y * bb.y; acc[1][2] += a.y * bb.z; acc[1][3] += a.y * bb.w;
            acc[2][0] += a.z * bb.x; acc[2][1] += a.z * bb.y; acc[2][2] += a.z * bb.z; acc[2][3] += a.z * bb.w;
            acc[3][0] += a.w * bb.x; acc[3][1] += a.w * bb.y; acc[3][2] += a.w * bb.z; acc[3][3] += a.w * bb.w;
        }
    }
#pragma unroll
    for (int i = 0; i < 4; i++) {
        int rl = ty * 4 + i;
        if (row0 + rl < cnt) {
            int tok = toks[rl];
            float4 o = make_float4(acc[i][0], acc[i][1], acc[i][2], acc[i][3]);
            *(float4*)(y + ((size_t)b * NN + tok) * DD + col0 + tx * 4) = o;
        }
    }
}

extern "C" void kernel_launch(void* const* d_in, const int* in_sizes, int n_in,
                              void* d_out, int out_size, void* d_ws, size_t ws_size,
                              hipStream_t stream) {
    const float* x       = (const float*)d_in[0];
    const float* gw      = (const float*)d_in[1];
    const float* experts = (const float*)d_in[2];
    float* y = (float*)d_out;

    char* ws = (char*)d_ws;
    float*    gates    = (float*)(ws + OFF_GATES);
    float*    topk_val = (float*)(ws + OFF_TOPK);
    int*      win      = (int*)(ws + OFF_WIN);
    int*      counts   = (int*)(ws + OFF_COUNTS);
    int*      lists    = (int*)(ws + OFF_LISTS);
    unsigned* bar      = (unsigned*)(ws + OFF_BAR);
    float*    part     = (float*)(ws + OFF_PART);
    unsigned long long* keys = (unsigned long long*)(ws + OFF_KEYS);
    bool big = ws_size >= WS_NEEDED;
    unsigned short* xbf  = big ? (unsigned short*)(ws + OFF_XBF)  : nullptr;
    unsigned short* expt = big ? (unsigned short*)(ws + OFF_EXPT) : nullptr;

    init_kernel<<<64, 256, 0, stream>>>(win, counts, bar);
    gate_logits_kernel<<<BN / 32, 256, 0, stream>>>(x, gw, gates, xbf);
    if (big) conv_experts_kernel<<<dim3(32, 32, 8), 256, 0, stream>>>(experts, expt);
    sinkhorn_mb<<<SBLK, 512, 0, stream>>>(gates, part, bar, keys);
    rank_topk_kernel<<<dim3(16, 32), 256, 0, stream>>>(keys, topk_val, win);
    build_lists_kernel<<<BN / 256, 256, 0, stream>>>(topk_val, win, counts, lists);
    zero_inactive_kernel<<<BN, 256, 0, stream>>>(win, y);
    if (big)
        expert_gemm_mfma<<<dim3(8, 4, BB * EE), 256, 0, stream>>>(xbf, expt, counts, lists, y);
    else
        expert_gemm_kernel<<<dim3(16, 8, BB * EE), 256, 0, stream>>>(x, experts, counts, lists, y);
}

// Round 5
// 351.554 us; speedup vs baseline: 1.5999x; 1.0416x over previous
//
#include <hip/hip_runtime.h>
#include <hip/hip_bf16.h>
#include <stdint.h>

#define BB 4
#define NN 4096
#define DD 1024
#define EE 8
#define MM 512
#define BN (BB*NN)   // 16384

#define SBLK 32      // sinkhorn blocks total
#define SPB  8       // slices per batch
#define SROWS 512    // rows per slice

typedef __bf16 bf16x8 __attribute__((ext_vector_type(8)));
typedef float  floatx4 __attribute__((ext_vector_type(4)));

typedef const __attribute__((address_space(1))) void* gptr_t;
typedef __attribute__((address_space(3))) void* lptr_t;

__device__ __forceinline__ unsigned short f2bf(float f) {
    union { float f; unsigned u; } v; v.f = f;
    unsigned r = v.u + 0x7fffu + ((v.u >> 16) & 1u);   // round-to-nearest-even
    return (unsigned short)(r >> 16);
}

// ---------------- ws layout (bytes) ----------------
#define OFF_GATES   0u                             // logits, 524288
#define OFF_TOPK    524288u                        // 65536
#define OFF_WIN     589824u                        // 65536
#define OFF_COUNTS  655360u                        // 256
#define OFF_LISTS   655616u                        // 65536
#define OFF_FLAGS   721152u                        // 8 it * 32 slices * 64B = 16384
#define OFF_PART    737536u                        // 8 it * 32 slices * 64B = 16384
#define OFF_KEYS    753920u                        // 32*4096*8 = 1048576
#define OFF_XBF     1802496u                       // BN*DD*2 = 33554432
#define OFF_EXPT    35356928u                      // EE*DD*DD*2 = 16777216
#define WS_NEEDED   52134144u

__global__ __launch_bounds__(256) void init_kernel(int* __restrict__ win, int* __restrict__ counts,
                                                   unsigned* __restrict__ flags) {
    int i = blockIdx.x * 256 + threadIdx.x;
    if (i < BN) win[i] = -1;
    if (i < 32) counts[i] = 0;
    if (i < 4096) flags[i] = 0u;   // 8 iters * 32 slices * 16 uints
}

// gw held fully in per-lane registers; 8 tokens per wave; also emits x in bf16.
__global__ __launch_bounds__(256) void gate_logits_kernel(const float* __restrict__ x,
                                                          const float* __restrict__ gw,
                                                          float* __restrict__ tmat,
                                                          unsigned short* __restrict__ xbf) {
    int tid = threadIdx.x;
    int wave = tid >> 6, lane = tid & 63;
    float4 g0[4][4], g1[4][4];     // [j][r]: experts 0..3 / 4..7 for row j*256+lane*4+r
#pragma unroll
    for (int j = 0; j < 4; j++)
#pragma unroll
        for (int r = 0; r < 4; r++) {
            const float4* p = (const float4*)(gw + (size_t)(j * 256 + lane * 4 + r) * 8);
            g0[j][r] = p[0];
            g1[j][r] = p[1];
        }
    int tok0 = (blockIdx.x * 4 + wave) * 8;
    for (int tt = 0; tt < 8; tt++) {
        int tok = tok0 + tt;
        const float4* xr = (const float4*)(x + (size_t)tok * DD);
        float4 a03 = make_float4(0.f, 0.f, 0.f, 0.f);
        float4 a47 = make_float4(0.f, 0.f, 0.f, 0.f);
#pragma unroll
        for (int j = 0; j < 4; j++) {
            float4 xv = xr[j * 64 + lane];
            if (xbf) {
                ushort4 o; o.x = f2bf(xv.x); o.y = f2bf(xv.y); o.z = f2bf(xv.z); o.w = f2bf(xv.w);
                ((ushort4*)(xbf + (size_t)tok * DD))[j * 64 + lane] = o;
            }
            a03.x += xv.x * g0[j][0].x + xv.y * g0[j][1].x + xv.z * g0[j][2].x + xv.w * g0[j][3].x;
            a03.y += xv.x * g0[j][0].y + xv.y * g0[j][1].y + xv.z * g0[j][2].y + xv.w * g0[j][3].y;
            a03.z += xv.x * g0[j][0].z + xv.y * g0[j][1].z + xv.z * g0[j][2].z + xv.w * g0[j][3].z;
            a03.w += xv.x * g0[j][0].w + xv.y * g0[j][1].w + xv.z * g0[j][2].w + xv.w * g0[j][3].w;
            a47.x += xv.x * g1[j][0].x + xv.y * g1[j][1].x + xv.z * g1[j][2].x + xv.w * g1[j][3].x;
            a47.y += xv.x * g1[j][0].y + xv.y * g1[j][1].y + xv.z * g1[j][2].y + xv.w * g1[j][3].y;
            a47.z += xv.x * g1[j][0].z + xv.y * g1[j][1].z + xv.z * g1[j][2].z + xv.w * g1[j][3].z;
            a47.w += xv.x * g1[j][0].w + xv.y * g1[j][1].w + xv.z * g1[j][2].w + xv.w * g1[j][3].w;
        }
        float acc[8] = {a03.x, a03.y, a03.z, a03.w, a47.x, a47.y, a47.z, a47.w};
#pragma unroll
        for (int e = 0; e < EE; e++) {
            float v = acc[e];
            for (int off = 32; off > 0; off >>= 1) v += __shfl_down(v, off, 64);
            if (lane == 0) tmat[(size_t)tok * EE + e] = logf(fmaxf(v, 1e-6f));
        }
    }
}

// experts[e][k][col] fp32 -> expt[e][col][k] bf16 (transposed)
__global__ __launch_bounds__(256) void conv_experts_kernel(const float* __restrict__ E,
                                                           unsigned short* __restrict__ expt) {
    __shared__ float tile[32][33];
    int e = blockIdx.z, k0 = blockIdx.x * 32, c0 = blockIdx.y * 32;
    int tid = threadIdx.x;
    int r = tid >> 3, c4 = (tid & 7) * 4;
    float4 v = *(const float4*)(E + ((size_t)e * DD + k0 + r) * DD + c0 + c4);
    tile[r][c4 + 0] = v.x; tile[r][c4 + 1] = v.y; tile[r][c4 + 2] = v.z; tile[r][c4 + 3] = v.w;
    __syncthreads();
    int cc = tid >> 3, k4 = (tid & 7) * 4;
    ushort4 o;
    o.x = f2bf(tile[k4 + 0][cc]); o.y = f2bf(tile[k4 + 1][cc]);
    o.z = f2bf(tile[k4 + 2][cc]); o.w = f2bf(tile[k4 + 3][cc]);
    *(ushort4*)&expt[((size_t)e * DD + c0 + cc) * DD + k0 + k4] = o;
}

// 32 blocks (8/batch, 512 rows each, 1 row/thread), 8 iterations.
// Cross-slice exchange: data-carrying flags (release/acquire), no counter barrier.
// flags/part: line-padded per (iter,slice): index (it*32 + b*8 + sl) * 16
__global__ __launch_bounds__(512) void sinkhorn_mb(const float* __restrict__ tmat,
                                                   float* __restrict__ part,
                                                   unsigned* __restrict__ flags,
                                                   unsigned long long* __restrict__ keys) {
    int g = blockIdx.x;
    int b = g >> 3, sl = g & 7;
    int tid = threadIdx.x;
    int wave = tid >> 6, lane = tid & 63;
    int row = sl * SROWS + tid;
    const float* tr = tmat + ((size_t)b * NN + row) * EE;
    float tv[EE];
#pragma unroll
    for (int e = 0; e < EE; e++) tv[e] = tr[e];

    __shared__ float red[8][8];
    __shared__ float bcm[8];
    __shared__ float bsum[8];

    for (int it = 0; it < 8; it++) {
        // ---- block-local column max ----
        float cm[EE];
#pragma unroll
        for (int e = 0; e < EE; e++) {
            float m = tv[e];
            for (int off = 32; off > 0; off >>= 1) m = fmaxf(m, __shfl_down(m, off, 64));
            cm[e] = m;
        }
        if (lane == 0) {
#pragma unroll
            for (int e = 0; e < EE; e++) red[wave][e] = cm[e];
        }
        __syncthreads();
        if (tid < 8) {
            float m = red[0][tid];
#pragma unroll
            for (int w = 1; w < 8; w++) m = fmaxf(m, red[w][tid]);
            bcm[tid] = m;
        }
        __syncthreads();
        float bm[EE];
#pragma unroll
        for (int e = 0; e < EE; e++) bm[e] = bcm[e];
        __syncthreads();   // red reuse below
        // ---- block-local column sumexp ----
#pragma unroll
        for (int e = 0; e < EE; e++) {
            float s = expf(tv[e] - bm[e]);
            for (int off = 32; off > 0; off >>= 1) s += __shfl_down(s, off, 64);
            cm[e] = s;   // reuse reg
        }
        if (lane == 0) {
#pragma unroll
            for (int e = 0; e < EE; e++) red[wave][e] = cm[e];
        }
        __syncthreads();
        if (tid < 8) {
            float s = 0.f;
#pragma unroll
            for (int w = 0; w < 8; w++) s += red[w][tid];
            bsum[tid] = s;
        }
        __syncthreads();
        // ---- publish this slice's (max, sum) + release flag (single thread) ----
        if (tid == 0) {
            float* pm = part + (size_t)(it * 32 + b * 8 + sl) * 16;
#pragma unroll
            for (int e = 0; e < EE; e++) {
                __hip_atomic_store(&pm[e],     bcm[e],  __ATOMIC_RELAXED, __HIP_MEMORY_SCOPE_AGENT);
                __hip_atomic_store(&pm[8 + e], bsum[e], __ATOMIC_RELAXED, __HIP_MEMORY_SCOPE_AGENT);
            }
            __hip_atomic_store(&flags[(size_t)(it * 32 + b * 8 + sl) * 16], 1u,
                               __ATOMIC_RELEASE, __HIP_MEMORY_SCOPE_AGENT);
        }
        // ---- poll the 8 slice flags of this batch (read-only, no RMW) ----
        if (tid < 8) {
            const unsigned* f = flags + (size_t)(it * 32 + b * 8 + tid) * 16;
            while (__hip_atomic_load(f, __ATOMIC_ACQUIRE, __HIP_MEMORY_SCOPE_AGENT) == 0u)
                __builtin_amdgcn_s_sleep(1);
        }
        __syncthreads();
        // ---- combine partials -> column LSE (thread e = tid) ----
        if (tid < 8) {
            const float* pb = part + (size_t)(it * 32 + b * 8) * 16;
            float ms[SPB], ss[SPB];
#pragma unroll
            for (int p = 0; p < SPB; p++) {
                ms[p] = __hip_atomic_load(&pb[p * 16 + tid],     __ATOMIC_RELAXED, __HIP_MEMORY_SCOPE_AGENT);
                ss[p] = __hip_atomic_load(&pb[p * 16 + 8 + tid], __ATOMIC_RELAXED, __HIP_MEMORY_SCOPE_AGENT);
            }
            float m = ms[0];
#pragma unroll
            for (int p = 1; p < SPB; p++) m = fmaxf(m, ms[p]);
            float stot = 0.f;
#pragma unroll
            for (int p = 0; p < SPB; p++) stot += ss[p] * expf(ms[p] - m);
            bcm[tid] = m + logf(stot);
        }
        __syncthreads();
#pragma unroll
        for (int e = 0; e < EE; e++) tv[e] -= bcm[e];
        // ---- row LSE (thread-local) ----
        {
            float m = tv[0];
#pragma unroll
            for (int e = 1; e < EE; e++) m = fmaxf(m, tv[e]);
            float s = 0.f;
#pragma unroll
            for (int e = 0; e < EE; e++) s += expf(tv[e] - m);
            float lse = m + logf(s);
#pragma unroll
            for (int e = 0; e < EE; e++) tv[e] -= lse;
        }
        __syncthreads();   // protect red/bcm for next iteration
    }
    // emit sort keys: gates in (0,1] positive -> u32 float-bit order == value order
#pragma unroll
    for (int e = 0; e < EE; e++) {
        unsigned fb = __float_as_uint(expf(tv[e]));
        keys[(size_t)(b * EE + e) * NN + row] =
            ((unsigned long long)fb << 32) | (unsigned)(~row);
    }
}

// exact rank by counting: rank(t) = #{j: key_j > key_t}; selected iff rank < 512.
__global__ __launch_bounds__(256) void rank_topk_kernel(const unsigned long long* __restrict__ keys,
                                                        float* __restrict__ topk_val,
                                                        int* __restrict__ win) {
    __shared__ unsigned long long K[NN];   // 32 KB
    int be = blockIdx.y;
    int b = be >> 3, e = be & 7;
    int tid = threadIdx.x;
    const unsigned long long* kcol = keys + (size_t)be * NN;
    for (int i = tid; i < NN / 2; i += 256)
        ((ulonglong2*)K)[i] = ((const ulonglong2*)kcol)[i];
    __syncthreads();
    int t = blockIdx.x * 256 + tid;
    unsigned long long my = K[t];
    int cnt = 0;
    for (int j = 0; j < NN; j += 8) {   // wave-uniform LDS reads -> broadcast, conflict-free
        ulonglong2 a = *(const ulonglong2*)&K[j + 0];
        ulonglong2 c = *(const ulonglong2*)&K[j + 2];
        ulonglong2 d = *(const ulonglong2*)&K[j + 4];
        ulonglong2 f = *(const ulonglong2*)&K[j + 6];
        cnt += (int)(a.x > my) + (int)(a.y > my) + (int)(c.x > my) + (int)(c.y > my)
             + (int)(d.x > my) + (int)(d.y > my) + (int)(f.x > my) + (int)(f.y > my);
    }
    if (cnt < MM) {
        topk_val[be * MM + cnt] = __uint_as_float((unsigned)(my >> 32));
        atomicMax(&win[b * NN + t], cnt * 8 + e);   // numpy scatter: max (m*8+e) wins
    }
}

__global__ __launch_bounds__(256) void build_lists_kernel(const float* __restrict__ topk_val,
                                                          int* __restrict__ win,
                                                          int* __restrict__ counts,
                                                          int* __restrict__ lists) {
    int i = blockIdx.x * 256 + threadIdx.x;
    if (i >= BN) return;
    int b = i >> 12, tok = i & 4095;
    int w = win[i];
    int active = 0;
    if (w >= 0) {
        int m = w >> 3, e = w & 7;
        float gv = topk_val[(b * 8 + e) * MM + m];
        if (gv > 0.5f) {
            int p = atomicAdd(&counts[b * 8 + e], 1);
            lists[(b * 8 + e) * MM + p] = tok;
            active = 1;
        }
    }
    win[i] = active;
}

__global__ __launch_bounds__(256) void zero_inactive_kernel(const int* __restrict__ act,
                                                            float* __restrict__ y) {
    int t = blockIdx.x;
    if (act[t]) return;
    float4* row = (float4*)(y + (size_t)t * DD);
    row[threadIdx.x] = make_float4(0.f, 0.f, 0.f, 0.f);
}

// ---------- bf16 MFMA gathered GEMM: y[b,tok,:] = xbf[b,tok,:] @ expt[e]^T ----------
__global__ __launch_bounds__(256) void expert_gemm_mfma(const unsigned short* __restrict__ xbf,
                                                        const unsigned short* __restrict__ expt,
                                                        const int* __restrict__ counts,
                                                        const int* __restrict__ lists,
                                                        float* __restrict__ y) {
    int be = blockIdx.z;
    int b = be >> 3, e = be & 7;
    int cnt = counts[be];
    int row0 = blockIdx.y * 128;
    if (row0 >= cnt) return;
    int col0 = blockIdx.x * 128;

    __shared__ unsigned short As[128 * 32];   // [row][k]
    __shared__ unsigned short Bs[128 * 32];   // [col][k]
    __shared__ int toks[128];

    int tid = threadIdx.x;
    int wave = tid >> 6, lane = tid & 63;
    int m16 = lane & 15, quad = lane >> 4;
    int wave_m = wave >> 1, wave_n = wave & 1;

    if (tid < 128) {
        int r = row0 + tid;
        toks[tid] = lists[be * MM + (r < cnt ? r : cnt - 1)];
    }

    int r0 = tid >> 2;
    int ch = tid & 3;

    const unsigned short* xb = xbf + (size_t)b * NN * DD;
    const unsigned short* Eb = expt + (size_t)e * DD * DD;

    floatx4 acc[4][4];
#pragma unroll
    for (int i = 0; i < 4; i++)
#pragma unroll
        for (int j = 0; j < 4; j++) acc[i][j] = (floatx4)0.f;

    for (int k0 = 0; k0 < DD; k0 += 32) {
        __syncthreads();
        {
            const unsigned short* gA0 = xb + (size_t)toks[r0] * DD + k0 + ch * 8;
            const unsigned short* gA1 = xb + (size_t)toks[64 + r0] * DD + k0 + ch * 8;
            const unsigned short* gB0 = Eb + (size_t)(col0 + r0) * DD + k0 + ch * 8;
            const unsigned short* gB1 = Eb + (size_t)(col0 + 64 + r0) * DD + k0 + ch * 8;
            __builtin_amdgcn_global_load_lds((gptr_t)gA0, (lptr_t)(As + (size_t)tid * 8), 16, 0, 0);
            __builtin_amdgcn_global_load_lds((gptr_t)gA1, (lptr_t)(As + 64 * 32 + (size_t)tid * 8), 16, 0, 0);
            __builtin_amdgcn_global_load_lds((gptr_t)gB0, (lptr_t)(Bs + (size_t)tid * 8), 16, 0, 0);
            __builtin_amdgcn_global_load_lds((gptr_t)gB1, (lptr_t)(Bs + 64 * 32 + (size_t)tid * 8), 16, 0, 0);
        }
        __syncthreads();
        bf16x8 af[4], bfr[4];
#pragma unroll
        for (int i = 0; i < 4; i++)
            af[i] = *(const bf16x8*)&As[(wave_m * 64 + i * 16 + m16) * 32 + quad * 8];
#pragma unroll
        for (int j = 0; j < 4; j++)
            bfr[j] = *(const bf16x8*)&Bs[(wave_n * 64 + j * 16 + m16) * 32 + quad * 8];
#pragma unroll
        for (int i = 0; i < 4; i++)
#pragma unroll
            for (int j = 0; j < 4; j++)
                acc[i][j] = __builtin_amdgcn_mfma_f32_16x16x32_bf16(af[i], bfr[j], acc[i][j], 0, 0, 0);
    }

#pragma unroll
    for (int i = 0; i < 4; i++) {
#pragma unroll
        for (int r = 0; r < 4; r++) {
            int lr = wave_m * 64 + i * 16 + quad * 4 + r;
            if (row0 + lr < cnt) {
                int tok = toks[lr];
                float* yr = y + ((size_t)b * NN + tok) * DD + col0 + wave_n * 64 + m16;
#pragma unroll
                for (int j = 0; j < 4; j++) yr[j * 16] = acc[i][j][r];
            }
        }
    }
}

// fallback fp32 GEMM (ws too small for bf16 buffers)
__global__ __launch_bounds__(256) void expert_gemm_kernel(const float* __restrict__ x,
                                                          const float* __restrict__ experts,
                                                          const int* __restrict__ counts,
                                                          const int* __restrict__ lists,
                                                          float* __restrict__ y) {
    int be = blockIdx.z;
    int b = be >> 3, e = be & 7;
    int cnt = counts[be];
    int row0 = blockIdx.y * 64;
    if (row0 >= cnt) return;
    int col0 = blockIdx.x * 64;
    __shared__ float As[16][68];
    __shared__ float Bs[16][68];
    __shared__ int toks[64];
    int tid = threadIdx.x;
    if (tid < 64) {
        int r = row0 + tid;
        toks[tid] = (r < cnt) ? lists[be * MM + r] : -1;
    }
    __syncthreads();
    int tx = tid & 15, ty = tid >> 4;
    int ar = tid >> 2;
    int ak = (tid & 3) * 4;
    int bk = tid >> 4;
    int bc4 = (tid & 15) * 4;
    int atok = toks[ar];
    const float* xb = x + (size_t)b * NN * DD;
    const float* Eb = experts + (size_t)e * DD * DD + col0;
    float acc[4][4] = {};
    for (int k0 = 0; k0 < DD; k0 += 16) {
        float4 av;
        if (atok >= 0) av = *(const float4*)(xb + (size_t)atok * DD + k0 + ak);
        else av = make_float4(0.f, 0.f, 0.f, 0.f);
        float4 bv = *(const float4*)(Eb + (size_t)(k0 + bk) * DD + bc4);
        __syncthreads();
        As[ak + 0][ar] = av.x; As[ak + 1][ar] = av.y; As[ak + 2][ar] = av.z; As[ak + 3][ar] = av.w;
        *(float4*)&Bs[bk][bc4] = bv;
        __syncthreads();
#pragma unroll
        for (int kk = 0; kk < 16; kk++) {
            float4 a = *(const float4*)&As[kk][ty * 4];
            float4 bb = *(const float4*)&Bs[kk][tx * 4];
            acc[0][0] += a.x * bb.x; acc[0][1] += a.x * bb.y; acc[0][2] += a.x * bb.z; acc[0][3] += a.x * bb.w;
            acc[1][0] += a.y * bb.x; acc[1][1] += a.y * bb.y; acc[1][2] += a.y * bb.z; acc[1][3] += a.y * bb.w;
            acc[2][0] += a.z * bb.x; acc[2][1] += a.z * bb.y; acc[2][2] += a.z * bb.z; acc[2][3] += a.z * bb.w;
            acc[3][0] += a.w * bb.x; acc[3][1] += a.w * bb.y; acc[3][2] += a.w * bb.z; acc[3][3] += a.w * bb.w;
        }
    }
#pragma unroll
    for (int i = 0; i < 4; i++) {
        int rl = ty * 4 + i;
        if (row0 + rl < cnt) {
            int tok = toks[rl];
            float4 o = make_float4(acc[i][0], acc[i][1], acc[i][2], acc[i][3]);
            *(float4*)(y + ((size_t)b * NN + tok) * DD + col0 + tx * 4) = o;
        }
    }
}

extern "C" void kernel_launch(void* const* d_in, const int* in_sizes, int n_in,
                              void* d_out, int out_size, void* d_ws, size_t ws_size,
                              hipStream_t stream) {
    const float* x       = (const float*)d_in[0];
    const float* gw      = (const float*)d_in[1];
    const float* experts = (const float*)d_in[2];
    float* y = (float*)d_out;

    char* ws = (char*)d_ws;
    float*    gates    = (float*)(ws + OFF_GATES);
    float*    topk_val = (float*)(ws + OFF_TOPK);
    int*      win      = (int*)(ws + OFF_WIN);
    int*      counts   = (int*)(ws + OFF_COUNTS);
    int*      lists    = (int*)(ws + OFF_LISTS);
    unsigned* flags    = (unsigned*)(ws + OFF_FLAGS);
    float*    part     = (float*)(ws + OFF_PART);
    unsigned long long* keys = (unsigned long long*)(ws + OFF_KEYS);
    bool big = ws_size >= WS_NEEDED;
    unsigned short* xbf  = big ? (unsigned short*)(ws + OFF_XBF)  : nullptr;
    unsigned short* expt = big ? (unsigned short*)(ws + OFF_EXPT) : nullptr;

    init_kernel<<<64, 256, 0, stream>>>(win, counts, flags);
    gate_logits_kernel<<<BN / 32, 256, 0, stream>>>(x, gw, gates, xbf);
    if (big) conv_experts_kernel<<<dim3(32, 32, 8), 256, 0, stream>>>(experts, expt);
    sinkhorn_mb<<<SBLK, 512, 0, stream>>>(gates, part, flags, keys);
    rank_topk_kernel<<<dim3(16, 32), 256, 0, stream>>>(keys, topk_val, win);
    build_lists_kernel<<<BN / 256, 256, 0, stream>>>(topk_val, win, counts, lists);
    zero_inactive_kernel<<<BN, 256, 0, stream>>>(win, y);
    if (big)
        expert_gemm_mfma<<<dim3(8, 4, BB * EE), 256, 0, stream>>>(xbf, expt, counts, lists, y);
    else
        expert_gemm_kernel<<<dim3(16, 8, BB * EE), 256, 0, stream>>>(x, experts, counts, lists, y);
}

// Round 6
// 307.341 us; speedup vs baseline: 1.8300x; 1.1439x over previous
//
#include <hip/hip_runtime.h>
#include <hip/hip_bf16.h>
#include <stdint.h>

#define BB 4
#define NN 4096
#define DD 1024
#define EE 8
#define MM 512
#define BN (BB*NN)   // 16384

#define SBLK 32      // sinkhorn blocks total
#define SPB  8       // slices per batch
#define SROWS 512    // rows per slice

// front kernel block ranges
#define FRONT_GATE 512
#define FRONT_CONV 2048
#define FRONT_INIT 64
#define FRONT_BLKS (FRONT_GATE + FRONT_CONV + FRONT_INIT)

typedef __bf16 bf16x8 __attribute__((ext_vector_type(8)));
typedef float  floatx4 __attribute__((ext_vector_type(4)));

typedef const __attribute__((address_space(1))) void* gptr_t;
typedef __attribute__((address_space(3))) void* lptr_t;

__device__ __forceinline__ unsigned short f2bf(float f) {
    union { float f; unsigned u; } v; v.f = f;
    unsigned r = v.u + 0x7fffu + ((v.u >> 16) & 1u);   // round-to-nearest-even
    return (unsigned short)(r >> 16);
}

// ---------------- ws layout (bytes) ----------------
#define OFF_GATES   0u                             // logits, 524288
#define OFF_TOPK    524288u                        // 65536
#define OFF_WIN     589824u                        // 65536
#define OFF_COUNTS  655360u                        // 256
#define OFF_LISTS   655616u                        // 65536
#define OFF_FLAGS   721152u                        // 8 it * 32 slices * 64B = 16384
#define OFF_PART    737536u                        // 8 it * 32 slices * 64B = 16384
#define OFF_KEYS    753920u                        // 32*4096*8 = 1048576
#define OFF_XBF     1802496u                       // BN*DD*2 = 33554432
#define OFF_EXPT    35356928u                      // EE*DD*DD*2 = 16777216
#define WS_NEEDED   52134144u

// ---- fused front: gate-logits (blocks 0..511) + expert bf16 transpose
// (512..2559) + state init (2560..2623). All independent work.
__global__ __launch_bounds__(256) void front_kernel(const float* __restrict__ x,
                                                    const float* __restrict__ gw,
                                                    const float* __restrict__ E,
                                                    float* __restrict__ tmat,
                                                    unsigned short* __restrict__ xbf,
                                                    unsigned short* __restrict__ expt,
                                                    int* __restrict__ win,
                                                    int* __restrict__ counts,
                                                    unsigned* __restrict__ flags) {
    __shared__ float tile[64][65];   // used by conv path only (16.6 KB)
    int bid = blockIdx.x;
    int tid = threadIdx.x;

    if (bid < FRONT_GATE) {
        // ---- gate logits: gw fully in registers, 8 tokens/wave ----
        int wave = tid >> 6, lane = tid & 63;
        float4 g0[4][4], g1[4][4];
#pragma unroll
        for (int j = 0; j < 4; j++)
#pragma unroll
            for (int r = 0; r < 4; r++) {
                const float4* p = (const float4*)(gw + (size_t)(j * 256 + lane * 4 + r) * 8);
                g0[j][r] = p[0];
                g1[j][r] = p[1];
            }
        int tok0 = (bid * 4 + wave) * 8;
        for (int tt = 0; tt < 8; tt++) {
            int tok = tok0 + tt;
            const float4* xr = (const float4*)(x + (size_t)tok * DD);
            float4 a03 = make_float4(0.f, 0.f, 0.f, 0.f);
            float4 a47 = make_float4(0.f, 0.f, 0.f, 0.f);
#pragma unroll
            for (int j = 0; j < 4; j++) {
                float4 xv = xr[j * 64 + lane];
                if (xbf) {
                    ushort4 o; o.x = f2bf(xv.x); o.y = f2bf(xv.y); o.z = f2bf(xv.z); o.w = f2bf(xv.w);
                    ((ushort4*)(xbf + (size_t)tok * DD))[j * 64 + lane] = o;
                }
                a03.x += xv.x * g0[j][0].x + xv.y * g0[j][1].x + xv.z * g0[j][2].x + xv.w * g0[j][3].x;
                a03.y += xv.x * g0[j][0].y + xv.y * g0[j][1].y + xv.z * g0[j][2].y + xv.w * g0[j][3].y;
                a03.z += xv.x * g0[j][0].z + xv.y * g0[j][1].z + xv.z * g0[j][2].z + xv.w * g0[j][3].z;
                a03.w += xv.x * g0[j][0].w + xv.y * g0[j][1].w + xv.z * g0[j][2].w + xv.w * g0[j][3].w;
                a47.x += xv.x * g1[j][0].x + xv.y * g1[j][1].x + xv.z * g1[j][2].x + xv.w * g1[j][3].x;
                a47.y += xv.x * g1[j][0].y + xv.y * g1[j][1].y + xv.z * g1[j][2].y + xv.w * g1[j][3].y;
                a47.z += xv.x * g1[j][0].z + xv.y * g1[j][1].z + xv.z * g1[j][2].z + xv.w * g1[j][3].z;
                a47.w += xv.x * g1[j][0].w + xv.y * g1[j][1].w + xv.z * g1[j][2].w + xv.w * g1[j][3].w;
            }
            float acc[8] = {a03.x, a03.y, a03.z, a03.w, a47.x, a47.y, a47.z, a47.w};
#pragma unroll
            for (int e = 0; e < EE; e++) {
                float v = acc[e];
                for (int off = 32; off > 0; off >>= 1) v += __shfl_down(v, off, 64);
                if (lane == 0) tmat[(size_t)tok * EE + e] = logf(fmaxf(v, 1e-6f));
            }
        }
    } else if (bid < FRONT_GATE + FRONT_CONV) {
        // ---- experts[e][k][c] fp32 -> expt[e][c][k] bf16, 64x64 tiles ----
        if (!expt) return;
        int cb = bid - FRONT_GATE;
        int e = cb >> 8, t = cb & 255;
        int k0 = (t >> 4) * 64, c0 = (t & 15) * 64;
#pragma unroll
        for (int ii = 0; ii < 4; ii++) {
            int r = (tid >> 4) + ii * 16;
            int c4 = (tid & 15) * 4;
            float4 v = *(const float4*)(E + ((size_t)e * DD + k0 + r) * DD + c0 + c4);
            tile[r][c4 + 0] = v.x; tile[r][c4 + 1] = v.y; tile[r][c4 + 2] = v.z; tile[r][c4 + 3] = v.w;
        }
        __syncthreads();
        int cc = tid >> 2, kk0 = (tid & 3) * 16;
#pragma unroll
        for (int q = 0; q < 4; q++) {
            ushort4 o;
            o.x = f2bf(tile[kk0 + q * 4 + 0][cc]);
            o.y = f2bf(tile[kk0 + q * 4 + 1][cc]);
            o.z = f2bf(tile[kk0 + q * 4 + 2][cc]);
            o.w = f2bf(tile[kk0 + q * 4 + 3][cc]);
            *(ushort4*)&expt[((size_t)e * DD + c0 + cc) * DD + k0 + kk0 + q * 4] = o;
        }
    } else {
        // ---- init ----
        int i = (bid - FRONT_GATE - FRONT_CONV) * 256 + tid;
        win[i] = -1;
        if (i < 32) counts[i] = 0;
        if (i < 4096) flags[i] = 0u;
    }
}

// 32 blocks (8/batch, 512 rows each, 1 row/thread), 8 iterations.
// Sum-only column LSE (no max subtraction: t bounded, exp can't overflow).
// Cross-slice exchange via data-carrying release/acquire flags, it-indexed.
__global__ __launch_bounds__(512) void sinkhorn_mb(const float* __restrict__ tmat,
                                                   float* __restrict__ part,
                                                   unsigned* __restrict__ flags,
                                                   unsigned long long* __restrict__ keys) {
    int g = blockIdx.x;
    int b = g >> 3, sl = g & 7;
    int tid = threadIdx.x;
    int wave = tid >> 6, lane = tid & 63;
    int row = sl * SROWS + tid;
    const float* tr = tmat + ((size_t)b * NN + row) * EE;
    float tv[EE];
#pragma unroll
    for (int e = 0; e < EE; e++) tv[e] = tr[e];

    __shared__ float red[8][8];   // [wave][expert]
    __shared__ float bcm[8];

    for (int it = 0; it < 8; it++) {
        // ---- block-local column sumexp (no max) ----
#pragma unroll
        for (int e = 0; e < EE; e++) {
            float s = expf(tv[e]);
            for (int off = 32; off > 0; off >>= 1) s += __shfl_down(s, off, 64);
            if (lane == 0) red[wave][e] = s;
        }
        __syncthreads();                         // (1) red ready
        if (tid == 0) {
            float* pm = part + (size_t)(it * 32 + b * 8 + sl) * 16;
#pragma unroll
            for (int e = 0; e < EE; e++) {
                float s = 0.f;
#pragma unroll
                for (int w = 0; w < 8; w++) s += red[w][e];
                __hip_atomic_store(&pm[e], s, __ATOMIC_RELAXED, __HIP_MEMORY_SCOPE_AGENT);
            }
            __hip_atomic_store(&flags[(size_t)(it * 32 + b * 8 + sl) * 16], 1u,
                               __ATOMIC_RELEASE, __HIP_MEMORY_SCOPE_AGENT);
        }
        if (tid < 8) {
            const unsigned* f = flags + (size_t)(it * 32 + b * 8 + tid) * 16;
            while (__hip_atomic_load(f, __ATOMIC_ACQUIRE, __HIP_MEMORY_SCOPE_AGENT) == 0u)
                __builtin_amdgcn_s_sleep(1);
        }
        __syncthreads();                         // (2) all slices arrived
        if (tid < 8) {
            const float* pb = part + (size_t)(it * 32 + b * 8) * 16;
            float s = 0.f;
#pragma unroll
            for (int p = 0; p < SPB; p++)
                s += __hip_atomic_load(&pb[p * 16 + tid], __ATOMIC_RELAXED, __HIP_MEMORY_SCOPE_AGENT);
            bcm[tid] = logf(s);
        }
        __syncthreads();                         // (3) bcm ready
#pragma unroll
        for (int e = 0; e < EE; e++) tv[e] -= bcm[e];
        // ---- row LSE (thread-local, no max) ----
        {
            float s = 0.f;
#pragma unroll
            for (int e = 0; e < EE; e++) s += expf(tv[e]);
            float lse = logf(s);
#pragma unroll
            for (int e = 0; e < EE; e++) tv[e] -= lse;
        }
    }
    // emit sort keys: gates in (0,1] positive -> u32 float-bit order == value order
#pragma unroll
    for (int e = 0; e < EE; e++) {
        unsigned fb = __float_as_uint(expf(tv[e]));
        keys[(size_t)(b * EE + e) * NN + row] =
            ((unsigned long long)fb << 32) | (unsigned)(~row);
    }
}

// exact rank by counting: rank(t) = #{j: key_j > key_t}; selected iff rank < 512.
__global__ __launch_bounds__(256) void rank_topk_kernel(const unsigned long long* __restrict__ keys,
                                                        float* __restrict__ topk_val,
                                                        int* __restrict__ win) {
    __shared__ unsigned long long K[NN];   // 32 KB
    int be = blockIdx.y;
    int b = be >> 3, e = be & 7;
    int tid = threadIdx.x;
    const unsigned long long* kcol = keys + (size_t)be * NN;
    for (int i = tid; i < NN / 2; i += 256)
        ((ulonglong2*)K)[i] = ((const ulonglong2*)kcol)[i];
    __syncthreads();
    int t = blockIdx.x * 256 + tid;
    unsigned long long my = K[t];
    int cnt = 0;
    for (int j = 0; j < NN; j += 8) {   // wave-uniform LDS reads -> broadcast
        ulonglong2 a = *(const ulonglong2*)&K[j + 0];
        ulonglong2 c = *(const ulonglong2*)&K[j + 2];
        ulonglong2 d = *(const ulonglong2*)&K[j + 4];
        ulonglong2 f = *(const ulonglong2*)&K[j + 6];
        cnt += (int)(a.x > my) + (int)(a.y > my) + (int)(c.x > my) + (int)(c.y > my)
             + (int)(d.x > my) + (int)(d.y > my) + (int)(f.x > my) + (int)(f.y > my);
    }
    if (cnt < MM) {
        topk_val[be * MM + cnt] = __uint_as_float((unsigned)(my >> 32));
        atomicMax(&win[b * NN + t], cnt * 8 + e);   // numpy scatter: max (m*8+e) wins
    }
}

// fused: resolve winners -> lists/counts, then zero inactive y rows.
// 256 blocks x 256 thr; block owns 64 tokens.
__global__ __launch_bounds__(256) void build_zero_kernel(const float* __restrict__ topk_val,
                                                         const int* __restrict__ win,
                                                         int* __restrict__ counts,
                                                         int* __restrict__ lists,
                                                         float* __restrict__ y) {
    __shared__ int act_s[64];
    int base = blockIdx.x * 64;
    int tid = threadIdx.x;
    if (tid < 64) {
        int i = base + tid;
        int b = i >> 12, tok = i & 4095;
        int w = win[i];
        int active = 0;
        if (w >= 0) {
            int m = w >> 3, e = w & 7;
            float gv = topk_val[(b * 8 + e) * MM + m];
            if (gv > 0.5f) {
                int p = atomicAdd(&counts[b * 8 + e], 1);
                lists[(b * 8 + e) * MM + p] = tok;
                active = 1;
            }
        }
        act_s[tid] = active;
    }
    __syncthreads();
    float4 z = make_float4(0.f, 0.f, 0.f, 0.f);
    for (int r = 0; r < 64; r++) {
        if (!act_s[r])
            ((float4*)(y + (size_t)(base + r) * DD))[tid] = z;
    }
}

// ---------- bf16 MFMA gathered GEMM: y[b,tok,:] = xbf[b,tok,:] @ expt[e]^T ----------
// 64x128 tile, BK=32; waves 2x2, each wave 2x4 of 16x16x32 MFMA (32x64 subtile)
__global__ __launch_bounds__(256) void expert_gemm_mfma(const unsigned short* __restrict__ xbf,
                                                        const unsigned short* __restrict__ expt,
                                                        const int* __restrict__ counts,
                                                        const int* __restrict__ lists,
                                                        float* __restrict__ y) {
    int be = blockIdx.z;
    int b = be >> 3, e = be & 7;
    int cnt = counts[be];
    int row0 = blockIdx.y * 64;
    if (row0 >= cnt) return;
    int col0 = blockIdx.x * 128;

    __shared__ unsigned short As[64 * 32];    // [row][k] 4 KB
    __shared__ unsigned short Bs[128 * 32];   // [col][k] 8 KB
    __shared__ int toks[64];

    int tid = threadIdx.x;
    int wave = tid >> 6, lane = tid & 63;
    int m16 = lane & 15, quad = lane >> 4;
    int wave_m = wave >> 1, wave_n = wave & 1;

    if (tid < 64) {
        int r = row0 + tid;
        toks[tid] = lists[be * MM + (r < cnt ? r : cnt - 1)];
    }

    int r0 = tid >> 2;          // staging row/col 0..63
    int ch = tid & 3;           // 16B chunk

    const unsigned short* xb = xbf + (size_t)b * NN * DD;
    const unsigned short* Eb = expt + (size_t)e * DD * DD;

    floatx4 acc[2][4];
#pragma unroll
    for (int i = 0; i < 2; i++)
#pragma unroll
        for (int j = 0; j < 4; j++) acc[i][j] = (floatx4)0.f;

    for (int k0 = 0; k0 < DD; k0 += 32) {
        __syncthreads();   // prev compute done (and toks visible on iter 0)
        {
            const unsigned short* gA  = xb + (size_t)toks[r0] * DD + k0 + ch * 8;
            const unsigned short* gB0 = Eb + (size_t)(col0 + r0) * DD + k0 + ch * 8;
            const unsigned short* gB1 = Eb + (size_t)(col0 + 64 + r0) * DD + k0 + ch * 8;
            __builtin_amdgcn_global_load_lds((gptr_t)gA,  (lptr_t)(As + (size_t)tid * 8), 16, 0, 0);
            __builtin_amdgcn_global_load_lds((gptr_t)gB0, (lptr_t)(Bs + (size_t)tid * 8), 16, 0, 0);
            __builtin_amdgcn_global_load_lds((gptr_t)gB1, (lptr_t)(Bs + 64 * 32 + (size_t)tid * 8), 16, 0, 0);
        }
        __syncthreads();   // drains vmcnt
        bf16x8 af[2], bfr[4];
#pragma unroll
        for (int i = 0; i < 2; i++)
            af[i] = *(const bf16x8*)&As[(wave_m * 32 + i * 16 + m16) * 32 + quad * 8];
#pragma unroll
        for (int j = 0; j < 4; j++)
            bfr[j] = *(const bf16x8*)&Bs[(wave_n * 64 + j * 16 + m16) * 32 + quad * 8];
#pragma unroll
        for (int i = 0; i < 2; i++)
#pragma unroll
            for (int j = 0; j < 4; j++)
                acc[i][j] = __builtin_amdgcn_mfma_f32_16x16x32_bf16(af[i], bfr[j], acc[i][j], 0, 0, 0);
    }

    // epilogue: C/D layout col=lane&15, row=quad*4+reg
#pragma unroll
    for (int i = 0; i < 2; i++) {
#pragma unroll
        for (int r = 0; r < 4; r++) {
            int lr = wave_m * 32 + i * 16 + quad * 4 + r;
            if (row0 + lr < cnt) {
                int tok = toks[lr];
                float* yr = y + ((size_t)b * NN + tok) * DD + col0 + wave_n * 64 + m16;
#pragma unroll
                for (int j = 0; j < 4; j++) yr[j * 16] = acc[i][j][r];
            }
        }
    }
}

// fallback fp32 GEMM (ws too small for bf16 buffers)
__global__ __launch_bounds__(256) void expert_gemm_kernel(const float* __restrict__ x,
                                                          const float* __restrict__ experts,
                                                          const int* __restrict__ counts,
                                                          const int* __restrict__ lists,
                                                          float* __restrict__ y) {
    int be = blockIdx.z;
    int b = be >> 3, e = be & 7;
    int cnt = counts[be];
    int row0 = blockIdx.y * 64;
    if (row0 >= cnt) return;
    int col0 = blockIdx.x * 64;
    __shared__ float As2[16][68];
    __shared__ float Bs2[16][68];
    __shared__ int toks[64];
    int tid = threadIdx.x;
    if (tid < 64) {
        int r = row0 + tid;
        toks[tid] = (r < cnt) ? lists[be * MM + r] : -1;
    }
    __syncthreads();
    int tx = tid & 15, ty = tid >> 4;
    int ar = tid >> 2;
    int ak = (tid & 3) * 4;
    int bk = tid >> 4;
    int bc4 = (tid & 15) * 4;
    int atok = toks[ar];
    const float* xb = x + (size_t)b * NN * DD;
    const float* Eb = experts + (size_t)e * DD * DD + col0;
    float acc[4][4] = {};
    for (int k0 = 0; k0 < DD; k0 += 16) {
        float4 av;
        if (atok >= 0) av = *(const float4*)(xb + (size_t)atok * DD + k0 + ak);
        else av = make_float4(0.f, 0.f, 0.f, 0.f);
        float4 bv = *(const float4*)(Eb + (size_t)(k0 + bk) * DD + bc4);
        __syncthreads();
        As2[ak + 0][ar] = av.x; As2[ak + 1][ar] = av.y; As2[ak + 2][ar] = av.z; As2[ak + 3][ar] = av.w;
        *(float4*)&Bs2[bk][bc4] = bv;
        __syncthreads();
#pragma unroll
        for (int kk = 0; kk < 16; kk++) {
            float4 a = *(const float4*)&As2[kk][ty * 4];
            float4 bb = *(const float4*)&Bs2[kk][tx * 4];
            acc[0][0] += a.x * bb.x; acc[0][1] += a.x * bb.y; acc[0][2] += a.x * bb.z; acc[0][3] += a.x * bb.w;
            acc[1][0] += a.y * bb.x; acc[1][1] += a.y * bb.y; acc[1][2] += a.y * bb.z; acc[1][3] += a.y * bb.w;
            acc[2][0] += a.z * bb.x; acc[2][1] += a.z * bb.y; acc[2][2] += a.z * bb.z; acc[2][3] += a.z * bb.w;
            acc[3][0] += a.w * bb.x; acc[3][1] += a.w * bb.y; acc[3][2] += a.w * bb.z; acc[3][3] += a.w * bb.w;
        }
    }
#pragma unroll
    for (int i = 0; i < 4; i++) {
        int rl = ty * 4 + i;
        if (row0 + rl < cnt) {
            int tok = toks[rl];
            float4 o = make_float4(acc[i][0], acc[i][1], acc[i][2], acc[i][3]);
            *(float4*)(y + ((size_t)b * NN + tok) * DD + col0 + tx * 4) = o;
        }
    }
}

extern "C" void kernel_launch(void* const* d_in, const int* in_sizes, int n_in,
                              void* d_out, int out_size, void* d_ws, size_t ws_size,
                              hipStream_t stream) {
    const float* x       = (const float*)d_in[0];
    const float* gw      = (const float*)d_in[1];
    const float* experts = (const float*)d_in[2];
    float* y = (float*)d_out;

    char* ws = (char*)d_ws;
    float*    gates    = (float*)(ws + OFF_GATES);
    float*    topk_val = (float*)(ws + OFF_TOPK);
    int*      win      = (int*)(ws + OFF_WIN);
    int*      counts   = (int*)(ws + OFF_COUNTS);
    int*      lists    = (int*)(ws + OFF_LISTS);
    unsigned* flags    = (unsigned*)(ws + OFF_FLAGS);
    float*    part     = (float*)(ws + OFF_PART);
    unsigned long long* keys = (unsigned long long*)(ws + OFF_KEYS);
    bool big = ws_size >= WS_NEEDED;
    unsigned short* xbf  = big ? (unsigned short*)(ws + OFF_XBF)  : nullptr;
    unsigned short* expt = big ? (unsigned short*)(ws + OFF_EXPT) : nullptr;

    front_kernel<<<FRONT_BLKS, 256, 0, stream>>>(x, gw, experts, gates, xbf, expt,
                                                 win, counts, flags);
    sinkhorn_mb<<<SBLK, 512, 0, stream>>>(gates, part, flags, keys);
    rank_topk_kernel<<<dim3(16, 32), 256, 0, stream>>>(keys, topk_val, win);
    build_zero_kernel<<<256, 256, 0, stream>>>(topk_val, win, counts, lists, y);
    if (big)
        expert_gemm_mfma<<<dim3(8, 8, BB * EE), 256, 0, stream>>>(xbf, expt, counts, lists, y);
    else
        expert_gemm_kernel<<<dim3(16, 8, BB * EE), 256, 0, stream>>>(x, experts, counts, lists, y);
}

// Round 7
// 293.670 us; speedup vs baseline: 1.9152x; 1.0465x over previous
//
#include <hip/hip_runtime.h>
#include <hip/hip_bf16.h>
#include <stdint.h>

#define BB 4
#define NN 4096
#define DD 1024
#define EE 8
#define MM 512
#define BN (BB*NN)   // 16384

#define SBLK 32      // sinkhorn blocks total
#define SPB  8       // slices per batch
#define SROWS 512    // rows per slice

// front kernel block ranges
#define FRONT_GATE 512
#define FRONT_CONV 2048
#define FRONT_INIT 64
#define FRONT_BLKS (FRONT_GATE + FRONT_CONV + FRONT_INIT)

typedef __bf16 bf16x8 __attribute__((ext_vector_type(8)));
typedef float  floatx4 __attribute__((ext_vector_type(4)));

typedef const __attribute__((address_space(1))) void* gptr_t;
typedef __attribute__((address_space(3))) void* lptr_t;

__device__ __forceinline__ unsigned short f2bf(float f) {
    union { float f; unsigned u; } v; v.f = f;
    unsigned r = v.u + 0x7fffu + ((v.u >> 16) & 1u);   // round-to-nearest-even
    return (unsigned short)(r >> 16);
}

// packed tree reduction: acc[8] per lane summed over 64 lanes.
// returns: lane l (any l) holds full sum of expert bitrev3(l&7) = ((l&1)<<2)|(l&2)|((l&4)>>2)
__device__ __forceinline__ float gate_reduce8(const float acc[8], int lane) {
    float k1[4];
#pragma unroll
    for (int e = 0; e < 4; e++) {
        float a = acc[e]     + __shfl_xor(acc[e],     1, 64);
        float b = acc[e + 4] + __shfl_xor(acc[e + 4], 1, 64);
        k1[e] = (lane & 1) ? b : a;
    }
    float k2[2];
#pragma unroll
    for (int e = 0; e < 2; e++) {
        float a = k1[e]     + __shfl_xor(k1[e],     2, 64);
        float b = k1[e + 2] + __shfl_xor(k1[e + 2], 2, 64);
        k2[e] = (lane & 2) ? b : a;
    }
    float a = k2[0] + __shfl_xor(k2[0], 4, 64);
    float b = k2[1] + __shfl_xor(k2[1], 4, 64);
    float v = (lane & 4) ? b : a;
    v += __shfl_xor(v, 8, 64);
    v += __shfl_xor(v, 16, 64);
    v += __shfl_xor(v, 32, 64);
    return v;
}

// ---------------- ws layout (bytes) ----------------
#define OFF_GATES   0u                             // logits, 524288
#define OFF_TOPK    524288u                        // 65536
#define OFF_WIN     589824u                        // 65536
#define OFF_COUNTS  655360u                        // 256
#define OFF_LISTS   655616u                        // 65536
#define OFF_FLAGS   721152u                        // 8 it * 32 slices * 64B = 16384
#define OFF_PART    737536u                        // 8 it * 32 slices * 64B = 16384
#define OFF_KEYS    753920u                        // 32*4096*8 = 1048576
#define OFF_XBF     1802496u                       // BN*DD*2 = 33554432
#define OFF_EXPT    35356928u                      // EE*DD*DD*2 = 16777216
#define WS_NEEDED   52134144u

// ---- fused front: gate-logits (blocks 0..511) + expert bf16 transpose
// (512..2559) + state init (2560..2623).
// __launch_bounds__(256,2): VGPR cap 256 so the 128-reg gw preload stays
// register-resident (round-6 failure: default cap ~85 forced gw reloads).
__global__ __launch_bounds__(256, 2) void front_kernel(const float* __restrict__ x,
                                                       const float* __restrict__ gw,
                                                       const float* __restrict__ E,
                                                       float* __restrict__ tmat,
                                                       unsigned short* __restrict__ xbf,
                                                       unsigned short* __restrict__ expt,
                                                       int* __restrict__ win,
                                                       int* __restrict__ counts,
                                                       unsigned* __restrict__ flags) {
    __shared__ float tile[64][65];   // conv path only (16.6 KB)
    int bid = blockIdx.x;
    int tid = threadIdx.x;

    if (bid < FRONT_GATE) {
        // ---- gate logits: gw fully in registers, 8 tokens/wave, 2-token interleave ----
        int wave = tid >> 6, lane = tid & 63;
        float4 g0[4][4], g1[4][4];     // [j][r]: experts 0..3 / 4..7 of row j*256+lane*4+r
#pragma unroll
        for (int j = 0; j < 4; j++)
#pragma unroll
            for (int r = 0; r < 4; r++) {
                const float4* p = (const float4*)(gw + (size_t)(j * 256 + lane * 4 + r) * 8);
                g0[j][r] = p[0];
                g1[j][r] = p[1];
            }
        int tok0 = (bid * 4 + wave) * 8;
        int exp_id = ((lane & 1) << 2) | (lane & 2) | ((lane & 4) >> 2);   // bitrev3
        for (int tt = 0; tt < 8; tt += 2) {
            int tokA = tok0 + tt, tokB = tokA + 1;
            const float4* xrA = (const float4*)(x + (size_t)tokA * DD);
            const float4* xrB = (const float4*)(x + (size_t)tokB * DD);
            float4 xa[4], xc[4];
#pragma unroll
            for (int j = 0; j < 4; j++) xa[j] = xrA[j * 64 + lane];
#pragma unroll
            for (int j = 0; j < 4; j++) xc[j] = xrB[j * 64 + lane];
            if (xbf) {
#pragma unroll
                for (int j = 0; j < 4; j++) {
                    ushort4 o;
                    o.x = f2bf(xa[j].x); o.y = f2bf(xa[j].y); o.z = f2bf(xa[j].z); o.w = f2bf(xa[j].w);
                    ((ushort4*)(xbf + (size_t)tokA * DD))[j * 64 + lane] = o;
                }
#pragma unroll
                for (int j = 0; j < 4; j++) {
                    ushort4 o;
                    o.x = f2bf(xc[j].x); o.y = f2bf(xc[j].y); o.z = f2bf(xc[j].z); o.w = f2bf(xc[j].w);
                    ((ushort4*)(xbf + (size_t)tokB * DD))[j * 64 + lane] = o;
                }
            }
            float accA[8] = {0.f, 0.f, 0.f, 0.f, 0.f, 0.f, 0.f, 0.f};
            float accB[8] = {0.f, 0.f, 0.f, 0.f, 0.f, 0.f, 0.f, 0.f};
#pragma unroll
            for (int j = 0; j < 4; j++) {
                accA[0] += xa[j].x * g0[j][0].x + xa[j].y * g0[j][1].x + xa[j].z * g0[j][2].x + xa[j].w * g0[j][3].x;
                accA[1] += xa[j].x * g0[j][0].y + xa[j].y * g0[j][1].y + xa[j].z * g0[j][2].y + xa[j].w * g0[j][3].y;
                accA[2] += xa[j].x * g0[j][0].z + xa[j].y * g0[j][1].z + xa[j].z * g0[j][2].z + xa[j].w * g0[j][3].z;
                accA[3] += xa[j].x * g0[j][0].w + xa[j].y * g0[j][1].w + xa[j].z * g0[j][2].w + xa[j].w * g0[j][3].w;
                accA[4] += xa[j].x * g1[j][0].x + xa[j].y * g1[j][1].x + xa[j].z * g1[j][2].x + xa[j].w * g1[j][3].x;
                accA[5] += xa[j].x * g1[j][0].y + xa[j].y * g1[j][1].y + xa[j].z * g1[j][2].y + xa[j].w * g1[j][3].y;
                accA[6] += xa[j].x * g1[j][0].z + xa[j].y * g1[j][1].z + xa[j].z * g1[j][2].z + xa[j].w * g1[j][3].z;
                accA[7] += xa[j].x * g1[j][0].w + xa[j].y * g1[j][1].w + xa[j].z * g1[j][2].w + xa[j].w * g1[j][3].w;
                accB[0] += xc[j].x * g0[j][0].x + xc[j].y * g0[j][1].x + xc[j].z * g0[j][2].x + xc[j].w * g0[j][3].x;
                accB[1] += xc[j].x * g0[j][0].y + xc[j].y * g0[j][1].y + xc[j].z * g0[j][2].y + xc[j].w * g0[j][3].y;
                accB[2] += xc[j].x * g0[j][0].z + xc[j].y * g0[j][1].z + xc[j].z * g0[j][2].z + xc[j].w * g0[j][3].z;
                accB[3] += xc[j].x * g0[j][0].w + xc[j].y * g0[j][1].w + xc[j].z * g0[j][2].w + xc[j].w * g0[j][3].w;
                accB[4] += xc[j].x * g1[j][0].x + xc[j].y * g1[j][1].x + xc[j].z * g1[j][2].x + xc[j].w * g1[j][3].x;
                accB[5] += xc[j].x * g1[j][0].y + xc[j].y * g1[j][1].y + xc[j].z * g1[j][2].y + xc[j].w * g1[j][3].y;
                accB[6] += xc[j].x * g1[j][0].z + xc[j].y * g1[j][1].z + xc[j].z * g1[j][2].z + xc[j].w * g1[j][3].z;
                accB[7] += xc[j].x * g1[j][0].w + xc[j].y * g1[j][1].w + xc[j].z * g1[j][2].w + xc[j].w * g1[j][3].w;
            }
            float vA = gate_reduce8(accA, lane);
            float vB = gate_reduce8(accB, lane);
            if (lane < 8) {
                tmat[(size_t)tokA * EE + exp_id] = logf(fmaxf(vA, 1e-6f));
                tmat[(size_t)tokB * EE + exp_id] = logf(fmaxf(vB, 1e-6f));
            }
        }
    } else if (bid < FRONT_GATE + FRONT_CONV) {
        // ---- experts[e][k][c] fp32 -> expt[e][c][k] bf16, 64x64 tiles ----
        if (!expt) return;
        int cb = bid - FRONT_GATE;
        int e = cb >> 8, t = cb & 255;
        int k0 = (t >> 4) * 64, c0 = (t & 15) * 64;
#pragma unroll
        for (int ii = 0; ii < 4; ii++) {
            int r = (tid >> 4) + ii * 16;
            int c4 = (tid & 15) * 4;
            float4 v = *(const float4*)(E + ((size_t)e * DD + k0 + r) * DD + c0 + c4);
            tile[r][c4 + 0] = v.x; tile[r][c4 + 1] = v.y; tile[r][c4 + 2] = v.z; tile[r][c4 + 3] = v.w;
        }
        __syncthreads();
        int cc = tid >> 2, kk0 = (tid & 3) * 16;
#pragma unroll
        for (int q = 0; q < 4; q++) {
            ushort4 o;
            o.x = f2bf(tile[kk0 + q * 4 + 0][cc]);
            o.y = f2bf(tile[kk0 + q * 4 + 1][cc]);
            o.z = f2bf(tile[kk0 + q * 4 + 2][cc]);
            o.w = f2bf(tile[kk0 + q * 4 + 3][cc]);
            *(ushort4*)&expt[((size_t)e * DD + c0 + cc) * DD + k0 + kk0 + q * 4] = o;
        }
    } else {
        // ---- init ----
        int i = (bid - FRONT_GATE - FRONT_CONV) * 256 + tid;
        win[i] = -1;
        if (i < 32) counts[i] = 0;
        if (i < 4096) flags[i] = 0u;
    }
}

// 32 blocks (8/batch, 512 rows each, 1 row/thread), 8 iterations.
// Sum-only column LSE; cross-slice exchange via data-carrying release/acquire flags.
__global__ __launch_bounds__(512) void sinkhorn_mb(const float* __restrict__ tmat,
                                                   float* __restrict__ part,
                                                   unsigned* __restrict__ flags,
                                                   unsigned long long* __restrict__ keys) {
    int g = blockIdx.x;
    int b = g >> 3, sl = g & 7;
    int tid = threadIdx.x;
    int wave = tid >> 6, lane = tid & 63;
    int row = sl * SROWS + tid;
    const float* tr = tmat + ((size_t)b * NN + row) * EE;
    float tv[EE];
#pragma unroll
    for (int e = 0; e < EE; e++) tv[e] = tr[e];

    __shared__ float red[8][8];   // [wave][expert]
    __shared__ float bcm[8];

    for (int it = 0; it < 8; it++) {
#pragma unroll
        for (int e = 0; e < EE; e++) {
            float s = expf(tv[e]);
            for (int off = 32; off > 0; off >>= 1) s += __shfl_down(s, off, 64);
            if (lane == 0) red[wave][e] = s;
        }
        __syncthreads();                         // (1) red ready
        if (tid == 0) {
            float* pm = part + (size_t)(it * 32 + b * 8 + sl) * 16;
#pragma unroll
            for (int e = 0; e < EE; e++) {
                float s = 0.f;
#pragma unroll
                for (int w = 0; w < 8; w++) s += red[w][e];
                __hip_atomic_store(&pm[e], s, __ATOMIC_RELAXED, __HIP_MEMORY_SCOPE_AGENT);
            }
            __hip_atomic_store(&flags[(size_t)(it * 32 + b * 8 + sl) * 16], 1u,
                               __ATOMIC_RELEASE, __HIP_MEMORY_SCOPE_AGENT);
        }
        if (tid < 8) {
            const unsigned* f = flags + (size_t)(it * 32 + b * 8 + tid) * 16;
            while (__hip_atomic_load(f, __ATOMIC_ACQUIRE, __HIP_MEMORY_SCOPE_AGENT) == 0u)
                __builtin_amdgcn_s_sleep(1);
        }
        __syncthreads();                         // (2) all slices arrived
        if (tid < 8) {
            const float* pb = part + (size_t)(it * 32 + b * 8) * 16;
            float s = 0.f;
#pragma unroll
            for (int p = 0; p < SPB; p++)
                s += __hip_atomic_load(&pb[p * 16 + tid], __ATOMIC_RELAXED, __HIP_MEMORY_SCOPE_AGENT);
            bcm[tid] = logf(s);
        }
        __syncthreads();                         // (3) bcm ready
#pragma unroll
        for (int e = 0; e < EE; e++) tv[e] -= bcm[e];
        {
            float s = 0.f;
#pragma unroll
            for (int e = 0; e < EE; e++) s += expf(tv[e]);
            float lse = logf(s);
#pragma unroll
            for (int e = 0; e < EE; e++) tv[e] -= lse;
        }
    }
#pragma unroll
    for (int e = 0; e < EE; e++) {
        unsigned fb = __float_as_uint(expf(tv[e]));
        keys[(size_t)(b * EE + e) * NN + row] =
            ((unsigned long long)fb << 32) | (unsigned)(~row);
    }
}

// exact rank by counting: rank(t) = #{j: key_j > key_t}; selected iff rank < 512.
__global__ __launch_bounds__(256) void rank_topk_kernel(const unsigned long long* __restrict__ keys,
                                                        float* __restrict__ topk_val,
                                                        int* __restrict__ win) {
    __shared__ unsigned long long K[NN];   // 32 KB
    int be = blockIdx.y;
    int b = be >> 3, e = be & 7;
    int tid = threadIdx.x;
    const unsigned long long* kcol = keys + (size_t)be * NN;
    for (int i = tid; i < NN / 2; i += 256)
        ((ulonglong2*)K)[i] = ((const ulonglong2*)kcol)[i];
    __syncthreads();
    int t = blockIdx.x * 256 + tid;
    unsigned long long my = K[t];
    int cnt = 0;
    for (int j = 0; j < NN; j += 8) {   // wave-uniform LDS reads -> broadcast
        ulonglong2 a = *(const ulonglong2*)&K[j + 0];
        ulonglong2 c = *(const ulonglong2*)&K[j + 2];
        ulonglong2 d = *(const ulonglong2*)&K[j + 4];
        ulonglong2 f = *(const ulonglong2*)&K[j + 6];
        cnt += (int)(a.x > my) + (int)(a.y > my) + (int)(c.x > my) + (int)(c.y > my)
             + (int)(d.x > my) + (int)(d.y > my) + (int)(f.x > my) + (int)(f.y > my);
    }
    if (cnt < MM) {
        topk_val[be * MM + cnt] = __uint_as_float((unsigned)(my >> 32));
        atomicMax(&win[b * NN + t], cnt * 8 + e);   // numpy scatter: max (m*8+e) wins
    }
}

// fused: resolve winners -> lists/counts, then zero inactive y rows.
__global__ __launch_bounds__(256) void build_zero_kernel(const float* __restrict__ topk_val,
                                                         const int* __restrict__ win,
                                                         int* __restrict__ counts,
                                                         int* __restrict__ lists,
                                                         float* __restrict__ y) {
    __shared__ int act_s[64];
    int base = blockIdx.x * 64;
    int tid = threadIdx.x;
    if (tid < 64) {
        int i = base + tid;
        int b = i >> 12, tok = i & 4095;
        int w = win[i];
        int active = 0;
        if (w >= 0) {
            int m = w >> 3, e = w & 7;
            float gv = topk_val[(b * 8 + e) * MM + m];
            if (gv > 0.5f) {
                int p = atomicAdd(&counts[b * 8 + e], 1);
                lists[(b * 8 + e) * MM + p] = tok;
                active = 1;
            }
        }
        act_s[tid] = active;
    }
    __syncthreads();
    float4 z = make_float4(0.f, 0.f, 0.f, 0.f);
    for (int r = 0; r < 64; r++) {
        if (!act_s[r])
            ((float4*)(y + (size_t)(base + r) * DD))[tid] = z;
    }
}

// ---------- bf16 MFMA gathered GEMM: y[b,tok,:] = xbf[b,tok,:] @ expt[e]^T ----------
// 64x128 tile, BK=32; waves 2x2, each wave 2x4 of 16x16x32 MFMA
__global__ __launch_bounds__(256) void expert_gemm_mfma(const unsigned short* __restrict__ xbf,
                                                        const unsigned short* __restrict__ expt,
                                                        const int* __restrict__ counts,
                                                        const int* __restrict__ lists,
                                                        float* __restrict__ y) {
    int be = blockIdx.z;
    int b = be >> 3, e = be & 7;
    int cnt = counts[be];
    int row0 = blockIdx.y * 64;
    if (row0 >= cnt) return;
    int col0 = blockIdx.x * 128;

    __shared__ unsigned short As[64 * 32];    // [row][k] 4 KB
    __shared__ unsigned short Bs[128 * 32];   // [col][k] 8 KB
    __shared__ int toks[64];

    int tid = threadIdx.x;
    int wave = tid >> 6, lane = tid & 63;
    int m16 = lane & 15, quad = lane >> 4;
    int wave_m = wave >> 1, wave_n = wave & 1;

    if (tid < 64) {
        int r = row0 + tid;
        toks[tid] = lists[be * MM + (r < cnt ? r : cnt - 1)];
    }

    int r0 = tid >> 2;
    int ch = tid & 3;

    const unsigned short* xb = xbf + (size_t)b * NN * DD;
    const unsigned short* Eb = expt + (size_t)e * DD * DD;

    floatx4 acc[2][4];
#pragma unroll
    for (int i = 0; i < 2; i++)
#pragma unroll
        for (int j = 0; j < 4; j++) acc[i][j] = (floatx4)0.f;

    for (int k0 = 0; k0 < DD; k0 += 32) {
        __syncthreads();
        {
            const unsigned short* gA  = xb + (size_t)toks[r0] * DD + k0 + ch * 8;
            const unsigned short* gB0 = Eb + (size_t)(col0 + r0) * DD + k0 + ch * 8;
            const unsigned short* gB1 = Eb + (size_t)(col0 + 64 + r0) * DD + k0 + ch * 8;
            __builtin_amdgcn_global_load_lds((gptr_t)gA,  (lptr_t)(As + (size_t)tid * 8), 16, 0, 0);
            __builtin_amdgcn_global_load_lds((gptr_t)gB0, (lptr_t)(Bs + (size_t)tid * 8), 16, 0, 0);
            __builtin_amdgcn_global_load_lds((gptr_t)gB1, (lptr_t)(Bs + 64 * 32 + (size_t)tid * 8), 16, 0, 0);
        }
        __syncthreads();
        bf16x8 af[2], bfr[4];
#pragma unroll
        for (int i = 0; i < 2; i++)
            af[i] = *(const bf16x8*)&As[(wave_m * 32 + i * 16 + m16) * 32 + quad * 8];
#pragma unroll
        for (int j = 0; j < 4; j++)
            bfr[j] = *(const bf16x8*)&Bs[(wave_n * 64 + j * 16 + m16) * 32 + quad * 8];
#pragma unroll
        for (int i = 0; i < 2; i++)
#pragma unroll
            for (int j = 0; j < 4; j++)
                acc[i][j] = __builtin_amdgcn_mfma_f32_16x16x32_bf16(af[i], bfr[j], acc[i][j], 0, 0, 0);
    }

#pragma unroll
    for (int i = 0; i < 2; i++) {
#pragma unroll
        for (int r = 0; r < 4; r++) {
            int lr = wave_m * 32 + i * 16 + quad * 4 + r;
            if (row0 + lr < cnt) {
                int tok = toks[lr];
                float* yr = y + ((size_t)b * NN + tok) * DD + col0 + wave_n * 64 + m16;
#pragma unroll
                for (int j = 0; j < 4; j++) yr[j * 16] = acc[i][j][r];
            }
        }
    }
}

// fallback fp32 GEMM (ws too small for bf16 buffers)
__global__ __launch_bounds__(256) void expert_gemm_kernel(const float* __restrict__ x,
                                                          const float* __restrict__ experts,
                                                          const int* __restrict__ counts,
                                                          const int* __restrict__ lists,
                                                          float* __restrict__ y) {
    int be = blockIdx.z;
    int b = be >> 3, e = be & 7;
    int cnt = counts[be];
    int row0 = blockIdx.y * 64;
    if (row0 >= cnt) return;
    int col0 = blockIdx.x * 64;
    __shared__ float As2[16][68];
    __shared__ float Bs2[16][68];
    __shared__ int toks[64];
    int tid = threadIdx.x;
    if (tid < 64) {
        int r = row0 + tid;
        toks[tid] = (r < cnt) ? lists[be * MM + r] : -1;
    }
    __syncthreads();
    int tx = tid & 15, ty = tid >> 4;
    int ar = tid >> 2;
    int ak = (tid & 3) * 4;
    int bk = tid >> 4;
    int bc4 = (tid & 15) * 4;
    int atok = toks[ar];
    const float* xb = x + (size_t)b * NN * DD;
    const float* Eb = experts + (size_t)e * DD * DD + col0;
    float acc[4][4] = {};
    for (int k0 = 0; k0 < DD; k0 += 16) {
        float4 av;
        if (atok >= 0) av = *(const float4*)(xb + (size_t)atok * DD + k0 + ak);
        else av = make_float4(0.f, 0.f, 0.f, 0.f);
        float4 bv = *(const float4*)(Eb + (size_t)(k0 + bk) * DD + bc4);
        __syncthreads();
        As2[ak + 0][ar] = av.x; As2[ak + 1][ar] = av.y; As2[ak + 2][ar] = av.z; As2[ak + 3][ar] = av.w;
        *(float4*)&Bs2[bk][bc4] = bv;
        __syncthreads();
#pragma unroll
        for (int kk = 0; kk < 16; kk++) {
            float4 a = *(const float4*)&As2[kk][ty * 4];
            float4 bb = *(const float4*)&Bs2[kk][tx * 4];
            acc[0][0] += a.x * bb.x; acc[0][1] += a.x * bb.y; acc[0][2] += a.x * bb.z; acc[0][3] += a.x * bb.w;
            acc[1][0] += a.y * bb.x; acc[1][1] += a.y * bb.y; acc[1][2] += a.y * bb.z; acc[1][3] += a.y * bb.w;
            acc[2][0] += a.z * bb.x; acc[2][1] += a.z * bb.y; acc[2][2] += a.z * bb.z; acc[2][3] += a.z * bb.w;
            acc[3][0] += a.w * bb.x; acc[3][1] += a.w * bb.y; acc[3][2] += a.w * bb.z; acc[3][3] += a.w * bb.w;
        }
    }
#pragma unroll
    for (int i = 0; i < 4; i++) {
        int rl = ty * 4 + i;
        if (row0 + rl < cnt) {
            int tok = toks[rl];
            float4 o = make_float4(acc[i][0], acc[i][1], acc[i][2], acc[i][3]);
            *(float4*)(y + ((size_t)b * NN + tok) * DD + col0 + tx * 4) = o;
        }
    }
}

extern "C" void kernel_launch(void* const* d_in, const int* in_sizes, int n_in,
                              void* d_out, int out_size, void* d_ws, size_t ws_size,
                              hipStream_t stream) {
    const float* x       = (const float*)d_in[0];
    const float* gw      = (const float*)d_in[1];
    const float* experts = (const float*)d_in[2];
    float* y = (float*)d_out;

    char* ws = (char*)d_ws;
    float*    gates    = (float*)(ws + OFF_GATES);
    float*    topk_val = (float*)(ws + OFF_TOPK);
    int*      win      = (int*)(ws + OFF_WIN);
    int*      counts   = (int*)(ws + OFF_COUNTS);
    int*      lists    = (int*)(ws + OFF_LISTS);
    unsigned* flags    = (unsigned*)(ws + OFF_FLAGS);
    float*    part     = (float*)(ws + OFF_PART);
    unsigned long long* keys = (unsigned long long*)(ws + OFF_KEYS);
    bool big = ws_size >= WS_NEEDED;
    unsigned short* xbf  = big ? (unsigned short*)(ws + OFF_XBF)  : nullptr;
    unsigned short* expt = big ? (unsigned short*)(ws + OFF_EXPT) : nullptr;

    front_kernel<<<FRONT_BLKS, 256, 0, stream>>>(x, gw, experts, gates, xbf, expt,
                                                 win, counts, flags);
    sinkhorn_mb<<<SBLK, 512, 0, stream>>>(gates, part, flags, keys);
    rank_topk_kernel<<<dim3(16, 32), 256, 0, stream>>>(keys, topk_val, win);
    build_zero_kernel<<<256, 256, 0, stream>>>(topk_val, win, counts, lists, y);
    if (big)
        expert_gemm_mfma<<<dim3(8, 8, BB * EE), 256, 0, stream>>>(xbf, expt, counts, lists, y);
    else
        expert_gemm_kernel<<<dim3(16, 8, BB * EE), 256, 0, stream>>>(x, experts, counts, lists, y);
}